// Round 5
// baseline (2913.154 us; speedup 1.0000x reference)
//
#include <hip/hip_runtime.h>
#include <hip/hip_bf16.h>

#define T_ 35
#define B_ 128
#define E_ 200
#define H_ 512
#define L_ 2
#define V_ 10000
#define BH_ (B_ * H_)
#define KPAD 224
#define NWG 64

typedef __attribute__((ext_vector_type(8))) short bf16x8;
typedef __attribute__((ext_vector_type(4))) float f32x4;

__device__ __forceinline__ unsigned short f2bf(float f) {
    union { float f; unsigned u; } c; c.f = f;
    unsigned r = c.u + 0x7FFF + ((c.u >> 16) & 1);
    return (unsigned short)(r >> 16);
}

// ---- agent-coherent (cache-bypassing) access helpers --------------------
__device__ __forceinline__ unsigned long long ald8(const unsigned short* p) {
    return __hip_atomic_load((unsigned long long*)p, __ATOMIC_RELAXED, __HIP_MEMORY_SCOPE_AGENT);
}
__device__ __forceinline__ float ald4f(const float* p) {
    return __hip_atomic_load((float*)p, __ATOMIC_RELAXED, __HIP_MEMORY_SCOPE_AGENT);
}
__device__ __forceinline__ void ast4f(float* p, float v) {
    __hip_atomic_store(p, v, __ATOMIC_RELAXED, __HIP_MEMORY_SCOPE_AGENT);
}
__device__ __forceinline__ bf16x8 mk8(unsigned long long lo, unsigned long long hi) {
    union { unsigned long long q[2]; bf16x8 v; } u; u.q[0] = lo; u.q[1] = hi; return u.v;
}
// pair-pack bf16 store: lanes l (even ccol) and l^1 exchange; even lane stores 4B.
__device__ __forceinline__ void store_pair_bf16(unsigned short* buf, int b, int h,
                                                float v, int lane) {
    float vn = __shfl_xor(v, 1);
    if ((lane & 1) == 0) {
        unsigned p = (unsigned)f2bf(v) | ((unsigned)f2bf(vn) << 16);
        __hip_atomic_store((unsigned*)(buf + b * 512 + h), p,
                           __ATOMIC_RELAXED, __HIP_MEMORY_SCOPE_AGENT);
    }
}

// ---------------------------------------------------------------- prep
__global__ void prep_all(const float* __restrict__ emb, const float* __restrict__ Wx0,
                         const float* __restrict__ Wx, const float* __restrict__ Wh,
                         const float* __restrict__ hidden,
                         unsigned short* embB, unsigned short* wx0cat,
                         unsigned short* whl0rf, unsigned short* whl0c,
                         unsigned short* w1rf, unsigned short* w1c,
                         float* h0f, unsigned short* h0b1,
                         float* h1f, unsigned short* h1b, int* bar) {
    int job = blockIdx.y;
    int stride = gridDim.x * blockDim.x;
    int i0 = blockIdx.x * blockDim.x + threadIdx.x;
    if (job == 0) {
        for (int i = i0; i < V_ * KPAD; i += stride) {
            int v = i / KPAD, k = i - v * KPAD;
            embB[i] = (k < E_) ? f2bf(emb[v * E_ + k]) : (unsigned short)0;
        }
    } else if (job == 1) {
        for (int i = i0; i < 1536 * KPAD; i += stride) {
            int n = i / KPAD, k = i - n * KPAD;
            wx0cat[i] = (k < E_) ? f2bf(Wx0[n * E_ + k]) : (unsigned short)0;
        }
    } else if (job == 2) {
        for (int i = i0; i < 1024 * 512; i += stride) whl0rf[i] = f2bf(Wh[i]);
    } else if (job == 3) {
        for (int i = i0; i < 512 * 512; i += stride) whl0c[i] = f2bf(Wh[524288 + i]);
    } else if (job == 4) {
        for (int i = i0; i < 1024 * 1024; i += stride) {
            int n = i >> 10, k = i & 1023;
            w1rf[i] = (k < 512) ? f2bf(Wx[n * 512 + k])
                                : f2bf(Wh[786432 + n * 512 + (k - 512)]);
        }
    } else if (job == 5) {
        for (int i = i0; i < 512 * 1024; i += stride) {
            int n = i >> 10, k = i & 1023;
            w1c[i] = (k < 512) ? f2bf(Wx[524288 + n * 512 + k])
                               : f2bf(Wh[1310720 + n * 512 + (k - 512)]);
        }
    } else {
        for (int i = i0; i < 2 * BH_; i += stride) {
            if (i < BH_) { h0f[i] = hidden[i]; h0b1[i] = f2bf(hidden[i]); }
            else { int k = i - BH_; h1f[k] = hidden[i]; h1b[k] = f2bf(hidden[i]); }
        }
        if (i0 == 0) bar[0] = 0;
    }
}

// ---------------------------------------------------------------- x-side GEMM
__global__ __launch_bounds__(256) void xside_gemm(
    const int* __restrict__ inputs, const unsigned short* __restrict__ embB,
    const unsigned short* __restrict__ wx0cat, float* __restrict__ gx0) {
    int m0 = blockIdx.x * 128, n0 = blockIdx.y * 128;
    int wave = threadIdx.x >> 6, lane = threadIdx.x & 63;
    int wr = wave >> 1, wc = wave & 1;
    int am = m0 + wr * 64, bn = n0 + wc * 64;
    int lr = lane & 15, lk = (lane >> 4) * 8;

    f32x4 acc[4][4] = {};
    int id[4];
    #pragma unroll
    for (int i = 0; i < 4; ++i) id[i] = inputs[am + i * 16 + lr];

    for (int k0 = 0; k0 < KPAD; k0 += 32) {
        bf16x8 a[4], b[4];
        #pragma unroll
        for (int i = 0; i < 4; ++i)
            a[i] = *(const bf16x8*)(embB + (size_t)id[i] * KPAD + k0 + lk);
        #pragma unroll
        for (int j = 0; j < 4; ++j)
            b[j] = *(const bf16x8*)(wx0cat + (size_t)(bn + j * 16 + lr) * KPAD + k0 + lk);
        #pragma unroll
        for (int i = 0; i < 4; ++i)
            #pragma unroll
            for (int j = 0; j < 4; ++j)
                acc[i][j] = __builtin_amdgcn_mfma_f32_16x16x32_bf16(a[i], b[j], acc[i][j], 0, 0, 0);
    }
    int crow0 = (lane >> 4) * 4, ccol = lane & 15;
    #pragma unroll
    for (int i = 0; i < 4; ++i) {
        #pragma unroll
        for (int r = 0; r < 4; ++r) {
            int row = am + i * 16 + crow0 + r;
            int t = row >> 7, b = row & 127;
            #pragma unroll
            for (int j = 0; j < 4; ++j) {
                int col = bn + j * 16 + ccol;
                int g = col >> 9, h = col & 511;
                gx0[((size_t)(t * 3 + g) * 128 + b) * 512 + h] = acc[i][j][r];
            }
        }
    }
}

// ---------------------------------------------------------------- scan
// Barrier: release-RMW (wbl2 is a no-op: L2 never dirtied — all communicated
// stores bypass it) + relaxed poll. NO acquire fence: all cross-WG data moves
// via per-access agent-coherent loads/stores, so weights stay L2-warm.
__device__ __forceinline__ void grid_bar(int* bar, int gen) {
    __syncthreads();
    if (threadIdx.x == 0) {
        __hip_atomic_fetch_add(bar, 1, __ATOMIC_RELEASE, __HIP_MEMORY_SCOPE_AGENT);
        while (__hip_atomic_load(bar, __ATOMIC_RELAXED, __HIP_MEMORY_SCOPE_AGENT) < gen * NWG)
            __builtin_amdgcn_s_sleep(2);
    }
    __syncthreads();
    __builtin_amdgcn_sched_barrier(0);
}

// 512-K half-GEMM: A via batch-issued coherent loads (pipelined), W plain (L2-warm).
template<int KW>
__device__ __forceinline__ void half_mfma(f32x4 acc[4], const unsigned short* A,
                                          const unsigned short* W, int kbase,
                                          int arow, int bcol0, int lane) {
    const int lr = lane & 15, lk = (lane >> 4) * 8;
    unsigned long long aq[16][2];
    #pragma unroll
    for (int c = 0; c < 16; ++c) {
        const unsigned short* ap = A + (size_t)arow * 512 + c * 32 + lk;
        aq[c][0] = ald8(ap);
        aq[c][1] = ald8(ap + 4);
    }
    #pragma unroll
    for (int c = 0; c < 16; ++c) {
        bf16x8 a = mk8(aq[c][0], aq[c][1]);
        #pragma unroll
        for (int j = 0; j < 4; ++j) {
            bf16x8 b = *(const bf16x8*)(W + (size_t)(bcol0 + j * 16 + lr) * KW + kbase + c * 32 + lk);
            acc[j] = __builtin_amdgcn_mfma_f32_16x16x32_bf16(a, b, acc[j], 0, 0, 0);
        }
    }
}

// Persistent 2-layer pipelined GRU scan. 64 WGs x 256 threads.
// slot 2t  : L0-P1(t)  [wg 0..31]  || L1-P1(t-1) [wg 32..63]
// slot 2t+1: L0-P2(t)  [wg 0..15]  || L1-P2(t-1) [wg 16..31]
__global__ __launch_bounds__(256) void scan_kernel(
    const float* __restrict__ gx0,
    const unsigned short* __restrict__ whl0rf, const unsigned short* __restrict__ whl0c,
    const unsigned short* __restrict__ w1rf, const unsigned short* __restrict__ w1c,
    const float* __restrict__ bh,
    float* h0f, unsigned short* h0b0, unsigned short* h0b1,
    float* h1f, unsigned short* h1b,
    unsigned short* rh0b, float* f0buf,
    unsigned short* rh1b, float* f1buf,
    unsigned short* h1bf, int* bar, float* hfinal_out) {
    const int wg = blockIdx.x;
    const int lane = threadIdx.x & 63;
    const int wave = threadIdx.x >> 6;
    const int wr = wave >> 1, wc = wave & 1;
    const int ccol = lane & 15, crow0 = (lane >> 4) * 4, lr = lane & 15;

    for (int s = 0; s <= 2 * T_ + 1; ++s) {
        if ((s & 1) == 0) {
            int t = s >> 1;
            if (wg < 32) {
                if (t < T_) {  // L0-P1(t): r,f gates
                    int bm0 = (wg & 3) * 32, bn0 = (wg >> 2) * 128;
                    int bm = bm0 + wr * 16, bc = bn0 + wc * 64;
                    const unsigned short* hprev = (t & 1) ? h0b0 : h0b1;
                    f32x4 acc[4] = {};
                    half_mfma<512>(acc, hprev, whl0rf, 0, bm + lr, bc, lane);
                    #pragma unroll
                    for (int j = 0; j < 4; ++j) {
                        int col = bc + j * 16 + ccol;
                        int g = col >> 9, h = col & 511;
                        float bias = bh[g * 512 + h];
                        const float* gx = gx0 + (size_t)(t * 3 + g) * BH_ + h;
                        #pragma unroll
                        for (int r = 0; r < 4; ++r) {
                            int b = bm + crow0 + r;
                            float v = acc[j][r] + gx[b * 512] + bias;
                            float sg = 1.f / (1.f + __expf(-v));
                            if (g == 0) {
                                float rh = sg * ald4f(h0f + b * 512 + h);
                                store_pair_bf16(rh0b, b, h, rh, lane);
                            } else {
                                ast4f(f0buf + b * 512 + h, sg);
                            }
                        }
                    }
                }
            } else {
                int tc = t - 1;
                if (tc >= 0 && tc < T_) {  // L1-P1(tc)
                    int wid = wg - 32;
                    int bm0 = (wid & 3) * 32, bn0 = (wid >> 2) * 128;
                    int bm = bm0 + wr * 16, bc = bn0 + wc * 64;
                    const unsigned short* h0cur = (tc & 1) ? h0b1 : h0b0;
                    f32x4 acc[4] = {};
                    half_mfma<1024>(acc, h0cur, w1rf, 0, bm + lr, bc, lane);
                    half_mfma<1024>(acc, h1b, w1rf, 512, bm + lr, bc, lane);
                    #pragma unroll
                    for (int j = 0; j < 4; ++j) {
                        int col = bc + j * 16 + ccol;
                        int g = col >> 9, h = col & 511;
                        float bias = bh[1536 + g * 512 + h];
                        #pragma unroll
                        for (int r = 0; r < 4; ++r) {
                            int b = bm + crow0 + r;
                            float v = acc[j][r] + bias;
                            float sg = 1.f / (1.f + __expf(-v));
                            if (g == 0) {
                                float rh = sg * ald4f(h1f + b * 512 + h);
                                store_pair_bf16(rh1b, b, h, rh, lane);
                            } else {
                                ast4f(f1buf + b * 512 + h, sg);
                            }
                        }
                    }
                }
            }
        } else {
            int t = s >> 1;
            if (wg < 16) {
                if (t < T_) {  // L0-P2(t): candidate + blend
                    int bm0 = (wg & 3) * 32, bn0 = (wg >> 2) * 128;
                    int bm = bm0 + wr * 16, bc = bn0 + wc * 64;
                    unsigned short* h0bw = (t & 1) ? h0b1 : h0b0;
                    f32x4 acc[4] = {};
                    half_mfma<512>(acc, rh0b, whl0c, 0, bm + lr, bc, lane);
                    #pragma unroll
                    for (int j = 0; j < 4; ++j) {
                        int h = bc + j * 16 + ccol;
                        float bias = bh[1024 + h];
                        const float* gx = gx0 + (size_t)(t * 3 + 2) * BH_ + h;
                        #pragma unroll
                        for (int r = 0; r < 4; ++r) {
                            int b = bm + crow0 + r;
                            float v = acc[j][r] + gx[b * 512] + bias;
                            float tld = tanhf(v);
                            float hp = ald4f(h0f + b * 512 + h);
                            float f = ald4f(f0buf + b * 512 + h);
                            float hn = hp + f * (tld - hp);
                            ast4f(h0f + b * 512 + h, hn);
                            store_pair_bf16(h0bw, b, h, hn, lane);
                        }
                    }
                }
            } else if (wg < 32) {
                int tc = t - 1;
                if (tc >= 0 && tc < T_) {  // L1-P2(tc)
                    int wid = wg - 16;
                    int bm0 = (wid & 3) * 32, bn0 = (wid >> 2) * 128;
                    int bm = bm0 + wr * 16, bc = bn0 + wc * 64;
                    const unsigned short* h0cur = (tc & 1) ? h0b1 : h0b0;
                    f32x4 acc[4] = {};
                    half_mfma<1024>(acc, h0cur, w1c, 0, bm + lr, bc, lane);
                    half_mfma<1024>(acc, rh1b, w1c, 512, bm + lr, bc, lane);
                    #pragma unroll
                    for (int j = 0; j < 4; ++j) {
                        int h = bc + j * 16 + ccol;
                        float bias = bh[2560 + h];
                        #pragma unroll
                        for (int r = 0; r < 4; ++r) {
                            int b = bm + crow0 + r;
                            float v = acc[j][r] + bias;
                            float tld = tanhf(v);
                            float hp = ald4f(h1f + b * 512 + h);
                            float f = ald4f(f1buf + b * 512 + h);
                            float hn = hp + f * (tld - hp);
                            ast4f(h1f + b * 512 + h, hn);
                            store_pair_bf16(h1b, b, h, hn, lane);
                            store_pair_bf16(h1bf + (size_t)tc * BH_, b, h, hn, lane);
                        }
                    }
                }
            }
        }
        grid_bar(bar, s + 1);
    }

    // final hidden -> out tail (coherent reads: plain loads could hit stale L2)
    for (int i = wg * 256 + threadIdx.x; i < BH_; i += NWG * 256) {
        hfinal_out[i] = ald4f(h0f + i);
        hfinal_out[BH_ + i] = ald4f(h1f + i);
    }
}

// ---------------------------------------------------------------- logits
__global__ __launch_bounds__(256) void logits_gemm(
    const unsigned short* __restrict__ A, const float* __restrict__ Wout,
    const float* __restrict__ bout, float* __restrict__ C) {
    const int K = H_;
    int m0 = blockIdx.x * 128, n0 = blockIdx.y * 128;
    int wave = threadIdx.x >> 6, lane = threadIdx.x & 63;
    int wr = wave >> 1, wc = wave & 1;
    int am = m0 + wr * 64, bn = n0 + wc * 64;
    int lr = lane & 15, lk = (lane >> 4) * 8;

    f32x4 acc[4][4] = {};
    for (int k0 = 0; k0 < K; k0 += 32) {
        bf16x8 a[4], b[4];
        #pragma unroll
        for (int i = 0; i < 4; ++i)
            a[i] = *(const bf16x8*)(A + (size_t)(am + i * 16 + lr) * K + k0 + lk);
        #pragma unroll
        for (int j = 0; j < 4; ++j) {
            int colc = bn + j * 16 + lr; if (colc >= V_) colc = V_ - 1;
            const float* wp = Wout + (size_t)colc * K + k0 + lk;
            float4 w0 = *(const float4*)wp;
            float4 w1 = *(const float4*)(wp + 4);
            bf16x8 bb;
            bb[0] = (short)f2bf(w0.x); bb[1] = (short)f2bf(w0.y);
            bb[2] = (short)f2bf(w0.z); bb[3] = (short)f2bf(w0.w);
            bb[4] = (short)f2bf(w1.x); bb[5] = (short)f2bf(w1.y);
            bb[6] = (short)f2bf(w1.z); bb[7] = (short)f2bf(w1.w);
            b[j] = bb;
        }
        #pragma unroll
        for (int i = 0; i < 4; ++i)
            #pragma unroll
            for (int j = 0; j < 4; ++j)
                acc[i][j] = __builtin_amdgcn_mfma_f32_16x16x32_bf16(a[i], b[j], acc[i][j], 0, 0, 0);
    }
    int crow0 = (lane >> 4) * 4, ccol = lane & 15;
    #pragma unroll
    for (int j = 0; j < 4; ++j) {
        int col = bn + j * 16 + ccol;
        if (col >= V_) continue;
        float bv = bout[col];
        #pragma unroll
        for (int i = 0; i < 4; ++i) {
            #pragma unroll
            for (int r = 0; r < 4; ++r) {
                int row = am + i * 16 + crow0 + r;
                __builtin_nontemporal_store(acc[i][j][r] + bv, &C[(size_t)row * V_ + col]);
            }
        }
    }
}

// ---------------------------------------------------------------- launch
extern "C" void kernel_launch(void* const* d_in, const int* in_sizes, int n_in,
                              void* d_out, int out_size, void* d_ws, size_t ws_size,
                              hipStream_t stream) {
    const int*   inputs = (const int*)  d_in[0];
    const float* hidden = (const float*)d_in[1];
    const float* emb    = (const float*)d_in[2];
    const float* Wx0    = (const float*)d_in[3];
    const float* Wx     = (const float*)d_in[4];
    const float* Wh     = (const float*)d_in[5];
    const float* bh     = (const float*)d_in[6];
    const float* Wout   = (const float*)d_in[7];
    const float* bout   = (const float*)d_in[8];
    float* out = (float*)d_out;
    (void)in_sizes; (void)n_in; (void)out_size; (void)ws_size;

    char* ws = (char*)d_ws;
    size_t off = 0;
    auto alloc = [&](size_t bytes) -> void* {
        void* p = ws + off;
        off += (bytes + 255) & ~(size_t)255;
        return p;
    };
    unsigned short* embB   = (unsigned short*)alloc((size_t)V_ * KPAD * 2);
    unsigned short* wx0cat = (unsigned short*)alloc((size_t)1536 * KPAD * 2);
    unsigned short* whl0rf = (unsigned short*)alloc((size_t)1024 * 512 * 2);
    unsigned short* whl0c  = (unsigned short*)alloc((size_t)512 * 512 * 2);
    unsigned short* w1rf   = (unsigned short*)alloc((size_t)1024 * 1024 * 2);
    unsigned short* w1c    = (unsigned short*)alloc((size_t)512 * 1024 * 2);
    unsigned short* h1bf   = (unsigned short*)alloc((size_t)T_ * BH_ * 2);
    float* h0f  = (float*)alloc(BH_ * 4);
    float* h1f  = (float*)alloc(BH_ * 4);
    unsigned short* h0b0 = (unsigned short*)alloc(BH_ * 2);
    unsigned short* h0b1 = (unsigned short*)alloc(BH_ * 2);
    unsigned short* h1b  = (unsigned short*)alloc(BH_ * 2);
    unsigned short* rh0b = (unsigned short*)alloc(BH_ * 2);
    unsigned short* rh1b = (unsigned short*)alloc(BH_ * 2);
    float* f0buf = (float*)alloc(BH_ * 4);
    float* f1buf = (float*)alloc(BH_ * 4);
    int* bar = (int*)alloc(256);

    // gx0 [T][3][128][512] f32 lives in d_out (27.5 MB); overwritten by logits later.
    float* gx0 = out;

    prep_all<<<dim3(1024, 7), dim3(256), 0, stream>>>(
        emb, Wx0, Wx, Wh, hidden, embB, wx0cat, whl0rf, whl0c, w1rf, w1c,
        h0f, h0b1, h1f, h1b, bar);
    xside_gemm<<<dim3(T_, 12), dim3(256), 0, stream>>>(inputs, embB, wx0cat, gx0);
    scan_kernel<<<dim3(NWG), dim3(256), 0, stream>>>(
        gx0, whl0rf, whl0c, w1rf, w1c, bh,
        h0f, h0b0, h0b1, h1f, h1b, rh0b, f0buf, rh1b, f1buf, h1bf, bar,
        out + (size_t)T_ * B_ * V_);
    logits_gemm<<<dim3(T_ * B_ / 128, (V_ + 127) / 128), dim3(256), 0, stream>>>(
        h1bf, Wout, bout, out);
}

// Round 6
// 2635.036 us; speedup vs baseline: 1.1055x; 1.1055x over previous
//
#include <hip/hip_runtime.h>
#include <hip/hip_bf16.h>

#define T_ 35
#define B_ 128
#define E_ 200
#define H_ 512
#define L_ 2
#define V_ 10000
#define BH_ (B_ * H_)
#define KPAD 224
#define NWG 64

typedef __attribute__((ext_vector_type(8))) short bf16x8;
typedef __attribute__((ext_vector_type(4))) float f32x4;

__device__ __forceinline__ unsigned short f2bf(float f) {
    union { float f; unsigned u; } c; c.f = f;
    unsigned r = c.u + 0x7FFF + ((c.u >> 16) & 1);
    return (unsigned short)(r >> 16);
}

// ---------------------------------------------------------------- prep
__global__ void prep_all(const float* __restrict__ emb, const float* __restrict__ Wx0,
                         const float* __restrict__ Wx, const float* __restrict__ Wh,
                         const float* __restrict__ hidden,
                         unsigned short* embB, unsigned short* wx0cat,
                         unsigned short* whl0rf, unsigned short* whl0c,
                         unsigned short* w1rf, unsigned short* w1c,
                         float* h0f, unsigned short* h0b1,
                         float* h1f, unsigned short* h1b, int* flags) {
    int job = blockIdx.y;
    int stride = gridDim.x * blockDim.x;
    int i0 = blockIdx.x * blockDim.x + threadIdx.x;
    if (job == 0) {
        for (int i = i0; i < V_ * KPAD; i += stride) {
            int v = i / KPAD, k = i - v * KPAD;
            embB[i] = (k < E_) ? f2bf(emb[v * E_ + k]) : (unsigned short)0;
        }
    } else if (job == 1) {
        for (int i = i0; i < 1536 * KPAD; i += stride) {
            int n = i / KPAD, k = i - n * KPAD;
            wx0cat[i] = (k < E_) ? f2bf(Wx0[n * E_ + k]) : (unsigned short)0;
        }
    } else if (job == 2) {
        for (int i = i0; i < 1024 * 512; i += stride) whl0rf[i] = f2bf(Wh[i]);
    } else if (job == 3) {
        for (int i = i0; i < 512 * 512; i += stride) whl0c[i] = f2bf(Wh[524288 + i]);
    } else if (job == 4) {
        for (int i = i0; i < 1024 * 1024; i += stride) {
            int n = i >> 10, k = i & 1023;
            w1rf[i] = (k < 512) ? f2bf(Wx[n * 512 + k])
                                : f2bf(Wh[786432 + n * 512 + (k - 512)]);
        }
    } else if (job == 5) {
        for (int i = i0; i < 512 * 1024; i += stride) {
            int n = i >> 10, k = i & 1023;
            w1c[i] = (k < 512) ? f2bf(Wx[524288 + n * 512 + k])
                               : f2bf(Wh[1310720 + n * 512 + (k - 512)]);
        }
    } else {
        for (int i = i0; i < 2 * BH_; i += stride) {
            if (i < BH_) { h0f[i] = hidden[i]; h0b1[i] = f2bf(hidden[i]); }
            else { int k = i - BH_; h1f[k] = hidden[i]; h1b[k] = f2bf(hidden[i]); }
        }
        for (int i = i0; i < NWG * 32; i += stride) flags[i] = 0;
    }
}

// ---------------------------------------------------------------- x-side GEMM
__global__ __launch_bounds__(256) void xside_gemm(
    const int* __restrict__ inputs, const unsigned short* __restrict__ embB,
    const unsigned short* __restrict__ wx0cat, float* __restrict__ gx0) {
    int m0 = blockIdx.x * 128, n0 = blockIdx.y * 128;
    int wave = threadIdx.x >> 6, lane = threadIdx.x & 63;
    int wr = wave >> 1, wc = wave & 1;
    int am = m0 + wr * 64, bn = n0 + wc * 64;
    int lr = lane & 15, lk = (lane >> 4) * 8;

    f32x4 acc[4][4] = {};
    int id[4];
    #pragma unroll
    for (int i = 0; i < 4; ++i) id[i] = inputs[am + i * 16 + lr];

    for (int k0 = 0; k0 < KPAD; k0 += 32) {
        bf16x8 a[4], b[4];
        #pragma unroll
        for (int i = 0; i < 4; ++i)
            a[i] = *(const bf16x8*)(embB + (size_t)id[i] * KPAD + k0 + lk);
        #pragma unroll
        for (int j = 0; j < 4; ++j)
            b[j] = *(const bf16x8*)(wx0cat + (size_t)(bn + j * 16 + lr) * KPAD + k0 + lk);
        #pragma unroll
        for (int i = 0; i < 4; ++i)
            #pragma unroll
            for (int j = 0; j < 4; ++j)
                acc[i][j] = __builtin_amdgcn_mfma_f32_16x16x32_bf16(a[i], b[j], acc[i][j], 0, 0, 0);
    }
    int crow0 = (lane >> 4) * 4, ccol = lane & 15;
    #pragma unroll
    for (int i = 0; i < 4; ++i) {
        #pragma unroll
        for (int r = 0; r < 4; ++r) {
            int row = am + i * 16 + crow0 + r;
            int t = row >> 7, b = row & 127;
            #pragma unroll
            for (int j = 0; j < 4; ++j) {
                int col = bn + j * 16 + ccol;
                int g = col >> 9, h = col & 511;
                gx0[((size_t)(t * 3 + g) * 128 + b) * 512 + h] = acc[i][j][r];
            }
        }
    }
}

// ---------------------------------------------------------------- scan
// Flag-array grid barrier: WG i RELEASE-stores gen to flags[i*32] (64 distinct
// 128B lines -> arrivals are parallel, each release wbl2-flushes its XCD's
// dirty L2 once). Wave 0 of EVERY WG polls all 64 flags (lane i <-> flag i,
// relaxed agent loads = one round-trip detect, no serialized RMW chain).
// One acquire fence per slot (L1/L2 inv) after the barrier.
__device__ __forceinline__ void grid_bar(int* flags, int gen) {
    __syncthreads();
    if (threadIdx.x == 0)
        __hip_atomic_store(flags + blockIdx.x * 32, gen, __ATOMIC_RELEASE,
                           __HIP_MEMORY_SCOPE_AGENT);
    if (threadIdx.x < NWG) {
        while (__hip_atomic_load(flags + threadIdx.x * 32, __ATOMIC_RELAXED,
                                 __HIP_MEMORY_SCOPE_AGENT) < gen)
            __builtin_amdgcn_s_sleep(1);
    }
    __syncthreads();
    __builtin_amdgcn_fence(__ATOMIC_ACQUIRE, "agent");
}

// 16-row x NF*16-col wave tile, K-accumulate. A rows stride 512 (A1|A2 concat
// when KW=1024). Plain cached loads (weights stay L2/L3-warm; state fresh
// post-fence).
template<int KW, int NF>
__device__ __forceinline__ void tile_mfma(f32x4 acc[NF], const unsigned short* A1,
                                          const unsigned short* A2, const unsigned short* W,
                                          int arow, int bcol0, int lane) {
    const int lr = lane & 15, lk = (lane >> 4) * 8;
    #pragma unroll
    for (int k0 = 0; k0 < KW; k0 += 32) {
        const unsigned short* ap = (k0 < 512) ? (A1 + (size_t)arow * 512 + k0 + lk)
                                              : (A2 + (size_t)arow * 512 + (k0 - 512) + lk);
        bf16x8 a = *(const bf16x8*)ap;
        #pragma unroll
        for (int j = 0; j < NF; ++j) {
            bf16x8 b = *(const bf16x8*)(W + (size_t)(bcol0 + j * 16 + lr) * KW + k0 + lk);
            acc[j] = __builtin_amdgcn_mfma_f32_16x16x32_bf16(a, b, acc[j], 0, 0, 0);
        }
    }
}

// Persistent 2-layer pipelined GRU scan. 64 WGs x 256 threads, ALL busy every slot.
// even slot 2t  : L0-P1(t)   [wg 0..31] || L1-P1(t-1) [wg 32..63]
// odd  slot 2t+1: L0-P2(t)   [wg 0..31] || L1-P2(t-1) [wg 32..63]
// P1 tile: rows 16 (rg=wg&7), waves cover 256 cols (cg=(wg&31)>>3): wave = 16x64.
// P2 tile: rows 16, waves cover 128 cols: wave = 16x32.
__global__ __launch_bounds__(256) void scan_kernel(
    const float* __restrict__ gx0,
    const unsigned short* __restrict__ whl0rf, const unsigned short* __restrict__ whl0c,
    const unsigned short* __restrict__ w1rf, const unsigned short* __restrict__ w1c,
    const float* __restrict__ bh,
    float* h0f, unsigned short* h0b0, unsigned short* h0b1,
    float* h1f, unsigned short* h1b,
    unsigned short* rh0b, float* f0buf,
    unsigned short* rh1b, float* f1buf,
    unsigned short* h1bf, int* flags, float* hfinal_out) {
    const int wg = blockIdx.x;
    const int lane = threadIdx.x & 63;
    const int wave = threadIdx.x >> 6;
    const int ccol = lane & 15, crow0 = (lane >> 4) * 4, lr = lane & 15;
    const int rg = wg & 7;
    const int cg = (wg & 31) >> 3;
    const int bm = rg * 16;

    for (int s = 0; s <= 2 * T_ + 1; ++s) {
        int t = s >> 1;
        if ((s & 1) == 0) {
            if (wg < 32) {
                if (t < T_) {  // L0-P1(t): r,f gates
                    int bc = cg * 256 + wave * 64;
                    const unsigned short* hprev = (t & 1) ? h0b0 : h0b1;
                    f32x4 acc[4] = {};
                    tile_mfma<512, 4>(acc, hprev, hprev, whl0rf, bm + lr, bc, lane);
                    #pragma unroll
                    for (int j = 0; j < 4; ++j) {
                        int col = bc + j * 16 + ccol;
                        int g = col >> 9, h = col & 511;
                        float bias = bh[g * 512 + h];
                        const float* gx = gx0 + (size_t)(t * 3 + g) * BH_ + h;
                        #pragma unroll
                        for (int r = 0; r < 4; ++r) {
                            int b = bm + crow0 + r;
                            float v = acc[j][r] + gx[b * 512] + bias;
                            float sg = 1.f / (1.f + __expf(-v));
                            if (g == 0) rh0b[b * 512 + h] = f2bf(sg * h0f[b * 512 + h]);
                            else        f0buf[b * 512 + h] = sg;
                        }
                    }
                }
            } else {
                int tc = t - 1;
                if (tc >= 0 && tc < T_) {  // L1-P1(tc)
                    int bc = cg * 256 + wave * 64;
                    const unsigned short* h0cur = (tc & 1) ? h0b1 : h0b0;
                    f32x4 acc[4] = {};
                    tile_mfma<1024, 4>(acc, h0cur, h1b, w1rf, bm + lr, bc, lane);
                    #pragma unroll
                    for (int j = 0; j < 4; ++j) {
                        int col = bc + j * 16 + ccol;
                        int g = col >> 9, h = col & 511;
                        float bias = bh[1536 + g * 512 + h];
                        #pragma unroll
                        for (int r = 0; r < 4; ++r) {
                            int b = bm + crow0 + r;
                            float v = acc[j][r] + bias;
                            float sg = 1.f / (1.f + __expf(-v));
                            if (g == 0) rh1b[b * 512 + h] = f2bf(sg * h1f[b * 512 + h]);
                            else        f1buf[b * 512 + h] = sg;
                        }
                    }
                }
            }
        } else {
            if (wg < 32) {
                if (t < T_) {  // L0-P2(t): candidate + blend
                    int bc = cg * 128 + wave * 32;
                    unsigned short* h0bw = (t & 1) ? h0b1 : h0b0;
                    f32x4 acc[2] = {};
                    tile_mfma<512, 2>(acc, rh0b, rh0b, whl0c, bm + lr, bc, lane);
                    #pragma unroll
                    for (int j = 0; j < 2; ++j) {
                        int h = bc + j * 16 + ccol;
                        float bias = bh[1024 + h];
                        const float* gx = gx0 + (size_t)(t * 3 + 2) * BH_ + h;
                        #pragma unroll
                        for (int r = 0; r < 4; ++r) {
                            int b = bm + crow0 + r;
                            float v = acc[j][r] + gx[b * 512] + bias;
                            float tld = tanhf(v);
                            float hp = h0f[b * 512 + h];
                            float f = f0buf[b * 512 + h];
                            float hn = hp + f * (tld - hp);
                            h0f[b * 512 + h] = hn;
                            h0bw[b * 512 + h] = f2bf(hn);
                        }
                    }
                }
            } else {
                int tc = t - 1;
                if (tc >= 0 && tc < T_) {  // L1-P2(tc)
                    int bc = cg * 128 + wave * 32;
                    const unsigned short* h0cur = (tc & 1) ? h0b1 : h0b0;
                    f32x4 acc[2] = {};
                    tile_mfma<1024, 2>(acc, h0cur, rh1b, w1c, bm + lr, bc, lane);
                    #pragma unroll
                    for (int j = 0; j < 2; ++j) {
                        int h = bc + j * 16 + ccol;
                        float bias = bh[2560 + h];
                        #pragma unroll
                        for (int r = 0; r < 4; ++r) {
                            int b = bm + crow0 + r;
                            float v = acc[j][r] + bias;
                            float tld = tanhf(v);
                            float hp = h1f[b * 512 + h];
                            float f = f1buf[b * 512 + h];
                            float hn = hp + f * (tld - hp);
                            h1f[b * 512 + h] = hn;
                            unsigned short hb = f2bf(hn);
                            h1b[b * 512 + h] = hb;
                            h1bf[(size_t)tc * BH_ + b * 512 + h] = hb;
                        }
                    }
                }
            }
        }
        grid_bar(flags, s + 1);
    }

    // final hidden -> out tail (post-final-barrier acquire fence: L2 fresh)
    for (int i = wg * 256 + threadIdx.x; i < BH_; i += NWG * 256) {
        hfinal_out[i] = h0f[i];
        hfinal_out[BH_ + i] = h1f[i];
    }
}

// ---------------------------------------------------------------- logits
__global__ __launch_bounds__(256) void logits_gemm(
    const unsigned short* __restrict__ A, const float* __restrict__ Wout,
    const float* __restrict__ bout, float* __restrict__ C) {
    const int K = H_;
    int m0 = blockIdx.x * 128, n0 = blockIdx.y * 128;
    int wave = threadIdx.x >> 6, lane = threadIdx.x & 63;
    int wr = wave >> 1, wc = wave & 1;
    int am = m0 + wr * 64, bn = n0 + wc * 64;
    int lr = lane & 15, lk = (lane >> 4) * 8;

    f32x4 acc[4][4] = {};
    for (int k0 = 0; k0 < K; k0 += 32) {
        bf16x8 a[4], b[4];
        #pragma unroll
        for (int i = 0; i < 4; ++i)
            a[i] = *(const bf16x8*)(A + (size_t)(am + i * 16 + lr) * K + k0 + lk);
        #pragma unroll
        for (int j = 0; j < 4; ++j) {
            int colc = bn + j * 16 + lr; if (colc >= V_) colc = V_ - 1;
            const float* wp = Wout + (size_t)colc * K + k0 + lk;
            float4 w0 = *(const float4*)wp;
            float4 w1 = *(const float4*)(wp + 4);
            bf16x8 bb;
            bb[0] = (short)f2bf(w0.x); bb[1] = (short)f2bf(w0.y);
            bb[2] = (short)f2bf(w0.z); bb[3] = (short)f2bf(w0.w);
            bb[4] = (short)f2bf(w1.x); bb[5] = (short)f2bf(w1.y);
            bb[6] = (short)f2bf(w1.z); bb[7] = (short)f2bf(w1.w);
            b[j] = bb;
        }
        #pragma unroll
        for (int i = 0; i < 4; ++i)
            #pragma unroll
            for (int j = 0; j < 4; ++j)
                acc[i][j] = __builtin_amdgcn_mfma_f32_16x16x32_bf16(a[i], b[j], acc[i][j], 0, 0, 0);
    }
    int crow0 = (lane >> 4) * 4, ccol = lane & 15;
    #pragma unroll
    for (int j = 0; j < 4; ++j) {
        int col = bn + j * 16 + ccol;
        if (col >= V_) continue;
        float bv = bout[col];
        #pragma unroll
        for (int i = 0; i < 4; ++i) {
            #pragma unroll
            for (int r = 0; r < 4; ++r) {
                int row = am + i * 16 + crow0 + r;
                __builtin_nontemporal_store(acc[i][j][r] + bv, &C[(size_t)row * V_ + col]);
            }
        }
    }
}

// ---------------------------------------------------------------- launch
extern "C" void kernel_launch(void* const* d_in, const int* in_sizes, int n_in,
                              void* d_out, int out_size, void* d_ws, size_t ws_size,
                              hipStream_t stream) {
    const int*   inputs = (const int*)  d_in[0];
    const float* hidden = (const float*)d_in[1];
    const float* emb    = (const float*)d_in[2];
    const float* Wx0    = (const float*)d_in[3];
    const float* Wx     = (const float*)d_in[4];
    const float* Wh     = (const float*)d_in[5];
    const float* bh     = (const float*)d_in[6];
    const float* Wout   = (const float*)d_in[7];
    const float* bout   = (const float*)d_in[8];
    float* out = (float*)d_out;
    (void)in_sizes; (void)n_in; (void)out_size; (void)ws_size;

    char* ws = (char*)d_ws;
    size_t off = 0;
    auto alloc = [&](size_t bytes) -> void* {
        void* p = ws + off;
        off += (bytes + 255) & ~(size_t)255;
        return p;
    };
    unsigned short* embB   = (unsigned short*)alloc((size_t)V_ * KPAD * 2);
    unsigned short* wx0cat = (unsigned short*)alloc((size_t)1536 * KPAD * 2);
    unsigned short* whl0rf = (unsigned short*)alloc((size_t)1024 * 512 * 2);
    unsigned short* whl0c  = (unsigned short*)alloc((size_t)512 * 512 * 2);
    unsigned short* w1rf   = (unsigned short*)alloc((size_t)1024 * 1024 * 2);
    unsigned short* w1c    = (unsigned short*)alloc((size_t)512 * 1024 * 2);
    unsigned short* h1bf   = (unsigned short*)alloc((size_t)T_ * BH_ * 2);
    float* h0f  = (float*)alloc(BH_ * 4);
    float* h1f  = (float*)alloc(BH_ * 4);
    unsigned short* h0b0 = (unsigned short*)alloc(BH_ * 2);
    unsigned short* h0b1 = (unsigned short*)alloc(BH_ * 2);
    unsigned short* h1b  = (unsigned short*)alloc(BH_ * 2);
    unsigned short* rh0b = (unsigned short*)alloc(BH_ * 2);
    unsigned short* rh1b = (unsigned short*)alloc(BH_ * 2);
    float* f0buf = (float*)alloc(BH_ * 4);
    float* f1buf = (float*)alloc(BH_ * 4);
    int* flags = (int*)alloc(NWG * 32 * 4);

    // gx0 [T][3][128][512] f32 lives in d_out (27.5 MB); overwritten by logits later.
    float* gx0 = out;

    prep_all<<<dim3(1024, 7), dim3(256), 0, stream>>>(
        emb, Wx0, Wx, Wh, hidden, embB, wx0cat, whl0rf, whl0c, w1rf, w1c,
        h0f, h0b1, h1f, h1b, flags);
    xside_gemm<<<dim3(T_, 12), dim3(256), 0, stream>>>(inputs, embB, wx0cat, gx0);
    scan_kernel<<<dim3(NWG), dim3(256), 0, stream>>>(
        gx0, whl0rf, whl0c, w1rf, w1c, bh,
        h0f, h0b0, h0b1, h1f, h1b, rh0b, f0buf, rh1b, f1buf, h1bf, flags,
        out + (size_t)T_ * B_ * V_);
    logits_gemm<<<dim3(T_ * B_ / 128, (V_ + 127) / 128), dim3(256), 0, stream>>>(
        h1bf, Wout, bout, out);
}

// Round 7
// 1389.897 us; speedup vs baseline: 2.0959x; 1.8958x over previous
//
#include <hip/hip_runtime.h>
#include <hip/hip_bf16.h>

#define T_ 35
#define B_ 128
#define E_ 200
#define H_ 512
#define L_ 2
#define V_ 10000
#define BH_ (B_ * H_)
#define KPAD 224
#define NWG 48

typedef __attribute__((ext_vector_type(8))) short bf16x8;
typedef __attribute__((ext_vector_type(4))) float f32x4;

__device__ __forceinline__ unsigned short f2bf(float f) {
    union { float f; unsigned u; } c; c.f = f;
    unsigned r = c.u + 0x7FFF + ((c.u >> 16) & 1);
    return (unsigned short)(r >> 16);
}

__device__ __forceinline__ bf16x8 cvt8(const float* src) {
    float4 w0 = *(const float4*)src;
    float4 w1 = *(const float4*)(src + 4);
    bf16x8 v;
    v[0] = (short)f2bf(w0.x); v[1] = (short)f2bf(w0.y);
    v[2] = (short)f2bf(w0.z); v[3] = (short)f2bf(w0.w);
    v[4] = (short)f2bf(w1.x); v[5] = (short)f2bf(w1.y);
    v[6] = (short)f2bf(w1.z); v[7] = (short)f2bf(w1.w);
    return v;
}

// ---------------------------------------------------------------- prep
// job 0: embB [V][224] bf16; job 1: wx0cat [1536][224] bf16; job 2: state+flags
__global__ void prep_all(const float* __restrict__ emb, const float* __restrict__ Wx0,
                         const float* __restrict__ hidden,
                         unsigned short* embB, unsigned short* wx0cat,
                         float* h0f, unsigned short* h0b1,
                         float* h1f, unsigned short* h1b, int* flags) {
    int job = blockIdx.y;
    int stride = gridDim.x * blockDim.x;
    int i0 = blockIdx.x * blockDim.x + threadIdx.x;
    if (job == 0) {
        for (int i = i0; i < V_ * KPAD; i += stride) {
            int v = i / KPAD, k = i - v * KPAD;
            embB[i] = (k < E_) ? f2bf(emb[v * E_ + k]) : (unsigned short)0;
        }
    } else if (job == 1) {
        for (int i = i0; i < 1536 * KPAD; i += stride) {
            int n = i / KPAD, k = i - n * KPAD;
            wx0cat[i] = (k < E_) ? f2bf(Wx0[n * E_ + k]) : (unsigned short)0;
        }
    } else {
        for (int i = i0; i < 2 * BH_; i += stride) {
            if (i < BH_) { h0f[i] = hidden[i]; h0b1[i] = f2bf(hidden[i]); }
            else { int k = i - BH_; h1f[k] = hidden[i]; h1b[k] = f2bf(hidden[i]); }
        }
        for (int i = i0; i < NWG * 32; i += stride) flags[i] = 0;
    }
}

// ---------------------------------------------------------------- x-side GEMM
__global__ __launch_bounds__(256) void xside_gemm(
    const int* __restrict__ inputs, const unsigned short* __restrict__ embB,
    const unsigned short* __restrict__ wx0cat, float* __restrict__ gx0) {
    int m0 = blockIdx.x * 128, n0 = blockIdx.y * 128;
    int wave = threadIdx.x >> 6, lane = threadIdx.x & 63;
    int wr = wave >> 1, wc = wave & 1;
    int am = m0 + wr * 64, bn = n0 + wc * 64;
    int lr = lane & 15, lk = (lane >> 4) * 8;

    f32x4 acc[4][4] = {};
    int id[4];
    #pragma unroll
    for (int i = 0; i < 4; ++i) id[i] = inputs[am + i * 16 + lr];

    for (int k0 = 0; k0 < KPAD; k0 += 32) {
        bf16x8 a[4], b[4];
        #pragma unroll
        for (int i = 0; i < 4; ++i)
            a[i] = *(const bf16x8*)(embB + (size_t)id[i] * KPAD + k0 + lk);
        #pragma unroll
        for (int j = 0; j < 4; ++j)
            b[j] = *(const bf16x8*)(wx0cat + (size_t)(bn + j * 16 + lr) * KPAD + k0 + lk);
        #pragma unroll
        for (int i = 0; i < 4; ++i)
            #pragma unroll
            for (int j = 0; j < 4; ++j)
                acc[i][j] = __builtin_amdgcn_mfma_f32_16x16x32_bf16(a[i], b[j], acc[i][j], 0, 0, 0);
    }
    int crow0 = (lane >> 4) * 4, ccol = lane & 15;
    #pragma unroll
    for (int i = 0; i < 4; ++i) {
        #pragma unroll
        for (int r = 0; r < 4; ++r) {
            int row = am + i * 16 + crow0 + r;
            int t = row >> 7, b = row & 127;
            #pragma unroll
            for (int j = 0; j < 4; ++j) {
                int col = bn + j * 16 + ccol;
                int g = col >> 9, h = col & 511;
                gx0[((size_t)(t * 3 + g) * 128 + b) * 512 + h] = acc[i][j][r];
            }
        }
    }
}

// ---------------------------------------------------------------- scan
// Flag-array barrier (parallel arrivals on distinct 128B lines) + one acquire
// fence per slot. Weights live in LDS (fence-immune) — only state refetches.
__device__ __forceinline__ void grid_bar(int* flags, int gen) {
    __syncthreads();
    if (threadIdx.x == 0)
        __hip_atomic_store(flags + blockIdx.x * 32, gen, __ATOMIC_RELEASE,
                           __HIP_MEMORY_SCOPE_AGENT);
    if (threadIdx.x < NWG) {
        while (__hip_atomic_load(flags + threadIdx.x * 32, __ATOMIC_RELAXED,
                                 __HIP_MEMORY_SCOPE_AGENT) < gen)
            __builtin_amdgcn_s_sleep(1);
    }
    __syncthreads();
    __builtin_amdgcn_fence(__ATOMIC_ACQUIRE, "agent");
}

// Persistent scan: 48 WGs x 512 threads (8 waves, 2/SIMD).
// wg 0..15  = L0, owns 32 cols/gate (LDS [96][512] bf16, swizzled).
// wg 16..47 = L1, owns 16 cols/gate (LDS [48][1024] bf16, swizzled).
// even slot 2t: L0-P1(t) || L1-P1(t-1);  odd: L0-P2(t) || L1-P2(t-1).
__global__ __launch_bounds__(512) void scan_kernel(
    const float* __restrict__ gx0,
    const float* __restrict__ Wx, const float* __restrict__ Wh,
    const float* __restrict__ bh,
    float* h0f, unsigned short* h0b0, unsigned short* h0b1,
    float* h1f, unsigned short* h1b,
    unsigned short* rh0b, float* f0buf,
    unsigned short* rh1b, float* f1buf,
    unsigned short* h1bf, int* flags, float* hfinal_out) {
    __shared__ unsigned short wlds[96 * 512];   // 96 KB

    const int tid = threadIdx.x;
    const int wg = blockIdx.x;
    const int lane = tid & 63;
    const int wave = tid >> 6;            // 0..7
    const int lr = lane & 15;
    const int hi = lane >> 4;             // 0..3
    const int lk8 = hi * 8;
    const int ccol = lane & 15;
    const int crow0 = hi * 4;
    const int row = wave * 16;            // wave's 16-row slice of B=128

    const bool isL0 = (wg < 16);
    const int wid = wg - 16;

    // ---- one-time LDS weight staging (f32 -> bf16, kg ^= (col&7) swizzle) ----
    if (isL0) {
        // local col lc 0..95: g=lc>>5, h=wg*32+(lc&31); K=512 (kg 0..63)
        for (int i = tid; i < 96 * 64; i += 512) {
            int lc = i >> 6, kg = i & 63;
            int g = lc >> 5, h = (wg << 5) + (lc & 31);
            const float* src = Wh + (size_t)(g * 512 + h) * 512 + kg * 8;
            *(bf16x8*)(wlds + lc * 512 + (kg ^ (lc & 7)) * 8) = cvt8(src);
        }
    } else {
        // local col lc 0..47: g=lc>>4, h=wid*16+(lc&15); K=1024 (kg 0..127)
        for (int i = tid; i < 48 * 128; i += 512) {
            int lc = i >> 7, kg = i & 127;
            int g = lc >> 4, h = (wid << 4) + (lc & 15);
            const float* src = (kg < 64)
                ? Wx + (size_t)(g * 512 + h) * 512 + kg * 8
                : Wh + (size_t)(3 * 512 * 512) + (size_t)(g * 512 + h) * 512 + (kg - 64) * 8;
            *(bf16x8*)(wlds + lc * 1024 + (kg ^ (lc & 7)) * 8) = cvt8(src);
        }
    }
    __syncthreads();

    for (int s = 0; s <= 2 * T_ + 1; ++s) {
        int t = s >> 1;
        if ((s & 1) == 0) {
            if (isL0) {
                if (t < T_) {  // ---- L0-P1(t): r,f gates over 64 owned cols
                    const unsigned short* hprev = (t & 1) ? h0b0 : h0b1;
                    bf16x8 a[16];
                    #pragma unroll
                    for (int ks = 0; ks < 16; ++ks)
                        a[ks] = *(const bf16x8*)(hprev + (size_t)(row + lr) * 512 + ks * 32 + lk8);
                    f32x4 acc[4] = {};
                    #pragma unroll
                    for (int ks = 0; ks < 16; ++ks) {
                        int kg = 4 * ks + hi;
                        #pragma unroll
                        for (int j = 0; j < 4; ++j) {
                            int c = j * 16 + lr;
                            bf16x8 b = *(const bf16x8*)(wlds + c * 512 + (kg ^ (c & 7)) * 8);
                            acc[j] = __builtin_amdgcn_mfma_f32_16x16x32_bf16(a[ks], b, acc[j], 0, 0, 0);
                        }
                    }
                    #pragma unroll
                    for (int j = 0; j < 4; ++j) {
                        int lc = j * 16 + ccol;
                        int g = lc >> 5, h = (wg << 5) + (lc & 31);
                        float bias = bh[g * 512 + h];
                        const float* gx = gx0 + (size_t)(t * 3 + g) * BH_ + h;
                        #pragma unroll
                        for (int r = 0; r < 4; ++r) {
                            int b = row + crow0 + r;
                            float v = acc[j][r] + gx[b * 512] + bias;
                            float sg = 1.f / (1.f + __expf(-v));
                            if (g == 0) rh0b[b * 512 + h] = f2bf(sg * h0f[b * 512 + h]);
                            else        f0buf[b * 512 + h] = sg;
                        }
                    }
                }
            } else {
                int tc = t - 1;
                if (tc >= 0 && tc < T_) {  // ---- L1-P1(tc): 32 owned cols, K=1024
                    const unsigned short* h0cur = (tc & 1) ? h0b1 : h0b0;
                    bf16x8 a0[16], a1[16];
                    #pragma unroll
                    for (int ks = 0; ks < 16; ++ks) {
                        a0[ks] = *(const bf16x8*)(h0cur + (size_t)(row + lr) * 512 + ks * 32 + lk8);
                        a1[ks] = *(const bf16x8*)(h1b + (size_t)(row + lr) * 512 + ks * 32 + lk8);
                    }
                    f32x4 acc[2] = {};
                    #pragma unroll
                    for (int ks = 0; ks < 16; ++ks) {
                        int kg = 4 * ks + hi;
                        #pragma unroll
                        for (int j = 0; j < 2; ++j) {
                            int c = j * 16 + lr;
                            bf16x8 b = *(const bf16x8*)(wlds + c * 1024 + (kg ^ (c & 7)) * 8);
                            acc[j] = __builtin_amdgcn_mfma_f32_16x16x32_bf16(a0[ks], b, acc[j], 0, 0, 0);
                        }
                    }
                    #pragma unroll
                    for (int ks = 0; ks < 16; ++ks) {
                        int kg = 64 + 4 * ks + hi;
                        #pragma unroll
                        for (int j = 0; j < 2; ++j) {
                            int c = j * 16 + lr;
                            bf16x8 b = *(const bf16x8*)(wlds + c * 1024 + (kg ^ (c & 7)) * 8);
                            acc[j] = __builtin_amdgcn_mfma_f32_16x16x32_bf16(a1[ks], b, acc[j], 0, 0, 0);
                        }
                    }
                    #pragma unroll
                    for (int j = 0; j < 2; ++j) {
                        int lc = j * 16 + ccol;
                        int g = lc >> 4, h = (wid << 4) + (lc & 15);
                        float bias = bh[1536 + g * 512 + h];
                        #pragma unroll
                        for (int r = 0; r < 4; ++r) {
                            int b = row + crow0 + r;
                            float v = acc[j][r] + bias;
                            float sg = 1.f / (1.f + __expf(-v));
                            if (g == 0) rh1b[b * 512 + h] = f2bf(sg * h1f[b * 512 + h]);
                            else        f1buf[b * 512 + h] = sg;
                        }
                    }
                }
            }
        } else {
            if (isL0) {
                if (t < T_) {  // ---- L0-P2(t): candidate (32 cols) + blend
                    unsigned short* h0bw = (t & 1) ? h0b1 : h0b0;
                    bf16x8 a[16];
                    #pragma unroll
                    for (int ks = 0; ks < 16; ++ks)
                        a[ks] = *(const bf16x8*)(rh0b + (size_t)(row + lr) * 512 + ks * 32 + lk8);
                    f32x4 acc[2] = {};
                    #pragma unroll
                    for (int ks = 0; ks < 16; ++ks) {
                        int kg = 4 * ks + hi;
                        #pragma unroll
                        for (int j = 0; j < 2; ++j) {
                            int c = 64 + j * 16 + lr;
                            bf16x8 b = *(const bf16x8*)(wlds + c * 512 + (kg ^ (c & 7)) * 8);
                            acc[j] = __builtin_amdgcn_mfma_f32_16x16x32_bf16(a[ks], b, acc[j], 0, 0, 0);
                        }
                    }
                    #pragma unroll
                    for (int j = 0; j < 2; ++j) {
                        int h = (wg << 5) + j * 16 + ccol;
                        float bias = bh[1024 + h];
                        const float* gx = gx0 + (size_t)(t * 3 + 2) * BH_ + h;
                        #pragma unroll
                        for (int r = 0; r < 4; ++r) {
                            int b = row + crow0 + r;
                            float v = acc[j][r] + gx[b * 512] + bias;
                            float tld = tanhf(v);
                            float hp = h0f[b * 512 + h];
                            float f = f0buf[b * 512 + h];
                            float hn = hp + f * (tld - hp);
                            h0f[b * 512 + h] = hn;
                            h0bw[b * 512 + h] = f2bf(hn);
                        }
                    }
                }
            } else {
                int tc = t - 1;
                if (tc >= 0 && tc < T_) {  // ---- L1-P2(tc): candidate (16 cols) + blend
                    const unsigned short* h0cur = (tc & 1) ? h0b1 : h0b0;
                    bf16x8 a0[16], a1[16];
                    #pragma unroll
                    for (int ks = 0; ks < 16; ++ks) {
                        a0[ks] = *(const bf16x8*)(h0cur + (size_t)(row + lr) * 512 + ks * 32 + lk8);
                        a1[ks] = *(const bf16x8*)(rh1b + (size_t)(row + lr) * 512 + ks * 32 + lk8);
                    }
                    f32x4 acc = {0.f, 0.f, 0.f, 0.f};
                    #pragma unroll
                    for (int ks = 0; ks < 16; ++ks) {
                        int kg = 4 * ks + hi;
                        int c = 32 + lr;
                        bf16x8 b = *(const bf16x8*)(wlds + c * 1024 + (kg ^ (c & 7)) * 8);
                        acc = __builtin_amdgcn_mfma_f32_16x16x32_bf16(a0[ks], b, acc, 0, 0, 0);
                    }
                    #pragma unroll
                    for (int ks = 0; ks < 16; ++ks) {
                        int kg = 64 + 4 * ks + hi;
                        int c = 32 + lr;
                        bf16x8 b = *(const bf16x8*)(wlds + c * 1024 + (kg ^ (c & 7)) * 8);
                        acc = __builtin_amdgcn_mfma_f32_16x16x32_bf16(a1[ks], b, acc, 0, 0, 0);
                    }
                    {
                        int h = (wid << 4) + ccol;
                        float bias = bh[2560 + h];
                        #pragma unroll
                        for (int r = 0; r < 4; ++r) {
                            int b = row + crow0 + r;
                            float v = acc[r] + bias;
                            float tld = tanhf(v);
                            float hp = h1f[b * 512 + h];
                            float f = f1buf[b * 512 + h];
                            float hn = hp + f * (tld - hp);
                            h1f[b * 512 + h] = hn;
                            unsigned short hb = f2bf(hn);
                            h1b[b * 512 + h] = hb;
                            h1bf[(size_t)tc * BH_ + b * 512 + h] = hb;
                        }
                    }
                }
            }
        }
        grid_bar(flags, s + 1);
    }

    // final hidden -> out tail (post-final-barrier fence: fresh)
    for (int i = wg * 512 + tid; i < BH_; i += NWG * 512) {
        hfinal_out[i] = h0f[i];
        hfinal_out[BH_ + i] = h1f[i];
    }
}

// ---------------------------------------------------------------- logits
__global__ __launch_bounds__(256) void logits_gemm(
    const unsigned short* __restrict__ A, const float* __restrict__ Wout,
    const float* __restrict__ bout, float* __restrict__ C) {
    const int K = H_;
    int m0 = blockIdx.x * 128, n0 = blockIdx.y * 128;
    int wave = threadIdx.x >> 6, lane = threadIdx.x & 63;
    int wr = wave >> 1, wc = wave & 1;
    int am = m0 + wr * 64, bn = n0 + wc * 64;
    int lr = lane & 15, lk = (lane >> 4) * 8;

    f32x4 acc[4][4] = {};
    for (int k0 = 0; k0 < K; k0 += 32) {
        bf16x8 a[4], b[4];
        #pragma unroll
        for (int i = 0; i < 4; ++i)
            a[i] = *(const bf16x8*)(A + (size_t)(am + i * 16 + lr) * K + k0 + lk);
        #pragma unroll
        for (int j = 0; j < 4; ++j) {
            int colc = bn + j * 16 + lr; if (colc >= V_) colc = V_ - 1;
            b[j] = cvt8(Wout + (size_t)colc * K + k0 + lk);
        }
        #pragma unroll
        for (int i = 0; i < 4; ++i)
            #pragma unroll
            for (int j = 0; j < 4; ++j)
                acc[i][j] = __builtin_amdgcn_mfma_f32_16x16x32_bf16(a[i], b[j], acc[i][j], 0, 0, 0);
    }
    int crow0 = (lane >> 4) * 4, ccol = lane & 15;
    #pragma unroll
    for (int j = 0; j < 4; ++j) {
        int col = bn + j * 16 + ccol;
        if (col >= V_) continue;
        float bv = bout[col];
        #pragma unroll
        for (int i = 0; i < 4; ++i) {
            #pragma unroll
            for (int r = 0; r < 4; ++r) {
                int row = am + i * 16 + crow0 + r;
                __builtin_nontemporal_store(acc[i][j][r] + bv, &C[(size_t)row * V_ + col]);
            }
        }
    }
}

// ---------------------------------------------------------------- launch
extern "C" void kernel_launch(void* const* d_in, const int* in_sizes, int n_in,
                              void* d_out, int out_size, void* d_ws, size_t ws_size,
                              hipStream_t stream) {
    const int*   inputs = (const int*)  d_in[0];
    const float* hidden = (const float*)d_in[1];
    const float* emb    = (const float*)d_in[2];
    const float* Wx0    = (const float*)d_in[3];
    const float* Wx     = (const float*)d_in[4];
    const float* Wh     = (const float*)d_in[5];
    const float* bh     = (const float*)d_in[6];
    const float* Wout   = (const float*)d_in[7];
    const float* bout   = (const float*)d_in[8];
    float* out = (float*)d_out;
    (void)in_sizes; (void)n_in; (void)out_size; (void)ws_size;

    char* ws = (char*)d_ws;
    size_t off = 0;
    auto alloc = [&](size_t bytes) -> void* {
        void* p = ws + off;
        off += (bytes + 255) & ~(size_t)255;
        return p;
    };
    unsigned short* embB   = (unsigned short*)alloc((size_t)V_ * KPAD * 2);
    unsigned short* wx0cat = (unsigned short*)alloc((size_t)1536 * KPAD * 2);
    unsigned short* h1bf   = (unsigned short*)alloc((size_t)T_ * BH_ * 2);
    float* h0f  = (float*)alloc(BH_ * 4);
    float* h1f  = (float*)alloc(BH_ * 4);
    unsigned short* h0b0 = (unsigned short*)alloc(BH_ * 2);
    unsigned short* h0b1 = (unsigned short*)alloc(BH_ * 2);
    unsigned short* h1b  = (unsigned short*)alloc(BH_ * 2);
    unsigned short* rh0b = (unsigned short*)alloc(BH_ * 2);
    unsigned short* rh1b = (unsigned short*)alloc(BH_ * 2);
    float* f0buf = (float*)alloc(BH_ * 4);
    float* f1buf = (float*)alloc(BH_ * 4);
    int* flags = (int*)alloc(NWG * 32 * 4);

    // gx0 [T][3][128][512] f32 lives in d_out; overwritten by logits later.
    float* gx0 = out;

    prep_all<<<dim3(1024, 3), dim3(256), 0, stream>>>(
        emb, Wx0, hidden, embB, wx0cat, h0f, h0b1, h1f, h1b, flags);
    xside_gemm<<<dim3(T_, 12), dim3(256), 0, stream>>>(inputs, embB, wx0cat, gx0);
    scan_kernel<<<dim3(NWG), dim3(512), 0, stream>>>(
        gx0, Wx, Wh, bh,
        h0f, h0b0, h0b1, h1f, h1b, rh0b, f0buf, rh1b, f1buf, h1bf, flags,
        out + (size_t)T_ * B_ * V_);
    logits_gemm<<<dim3(T_ * B_ / 128, (V_ + 127) / 128), dim3(256), 0, stream>>>(
        h1bf, Wout, bout, out);
}

// Round 8
// 966.232 us; speedup vs baseline: 3.0150x; 1.4385x over previous
//
#include <hip/hip_runtime.h>
#include <hip/hip_bf16.h>

#define T_ 35
#define B_ 128
#define E_ 200
#define H_ 512
#define L_ 2
#define V_ 10000
#define BH_ (B_ * H_)
#define KPAD 224
#define NWG 48

typedef __attribute__((ext_vector_type(8))) short bf16x8;
typedef __attribute__((ext_vector_type(4))) float f32x4;

__device__ __forceinline__ unsigned short f2bf(float f) {
    union { float f; unsigned u; } c; c.f = f;
    unsigned r = c.u + 0x7FFF + ((c.u >> 16) & 1);
    return (unsigned short)(r >> 16);
}

__device__ __forceinline__ bf16x8 cvt8(const float* src) {
    float4 w0 = *(const float4*)src;
    float4 w1 = *(const float4*)(src + 4);
    bf16x8 v;
    v[0] = (short)f2bf(w0.x); v[1] = (short)f2bf(w0.y);
    v[2] = (short)f2bf(w0.z); v[3] = (short)f2bf(w0.w);
    v[4] = (short)f2bf(w1.x); v[5] = (short)f2bf(w1.y);
    v[6] = (short)f2bf(w1.z); v[7] = (short)f2bf(w1.w);
    return v;
}

// ---------------------------------------------------------------- prep
// job 0: embB bf16; job 1: wx0cat bf16; job 2: state+flags; job 3: WoutB bf16
__global__ void prep_all(const float* __restrict__ emb, const float* __restrict__ Wx0,
                         const float* __restrict__ hidden, const float* __restrict__ Wout,
                         unsigned short* embB, unsigned short* wx0cat,
                         unsigned short* WoutB,
                         float* h0f, unsigned short* h0b1,
                         float* h1f, unsigned short* h1b, int* flags) {
    int job = blockIdx.y;
    int stride = gridDim.x * blockDim.x;
    int i0 = blockIdx.x * blockDim.x + threadIdx.x;
    if (job == 0) {
        for (int i = i0; i < V_ * KPAD; i += stride) {
            int v = i / KPAD, k = i - v * KPAD;
            embB[i] = (k < E_) ? f2bf(emb[v * E_ + k]) : (unsigned short)0;
        }
    } else if (job == 1) {
        for (int i = i0; i < 1536 * KPAD; i += stride) {
            int n = i / KPAD, k = i - n * KPAD;
            wx0cat[i] = (k < E_) ? f2bf(Wx0[n * E_ + k]) : (unsigned short)0;
        }
    } else if (job == 2) {
        for (int i = i0; i < 2 * BH_; i += stride) {
            if (i < BH_) { h0f[i] = hidden[i]; h0b1[i] = f2bf(hidden[i]); }
            else { int k = i - BH_; h1f[k] = hidden[i]; h1b[k] = f2bf(hidden[i]); }
        }
        for (int i = i0; i < NWG * 32; i += stride) flags[i] = 0;
    } else {
        for (int i = i0; i < V_ * H_; i += stride) WoutB[i] = f2bf(Wout[i]);
    }
}

// ---------------------------------------------------------------- x-side GEMM
__global__ __launch_bounds__(256) void xside_gemm(
    const int* __restrict__ inputs, const unsigned short* __restrict__ embB,
    const unsigned short* __restrict__ wx0cat, float* __restrict__ gx0) {
    int m0 = blockIdx.x * 128, n0 = blockIdx.y * 128;
    int wave = threadIdx.x >> 6, lane = threadIdx.x & 63;
    int wr = wave >> 1, wc = wave & 1;
    int am = m0 + wr * 64, bn = n0 + wc * 64;
    int lr = lane & 15, lk = (lane >> 4) * 8;

    f32x4 acc[4][4] = {};
    int id[4];
    #pragma unroll
    for (int i = 0; i < 4; ++i) id[i] = inputs[am + i * 16 + lr];

    for (int k0 = 0; k0 < KPAD; k0 += 32) {
        bf16x8 a[4], b[4];
        #pragma unroll
        for (int i = 0; i < 4; ++i)
            a[i] = *(const bf16x8*)(embB + (size_t)id[i] * KPAD + k0 + lk);
        #pragma unroll
        for (int j = 0; j < 4; ++j)
            b[j] = *(const bf16x8*)(wx0cat + (size_t)(bn + j * 16 + lr) * KPAD + k0 + lk);
        #pragma unroll
        for (int i = 0; i < 4; ++i)
            #pragma unroll
            for (int j = 0; j < 4; ++j)
                acc[i][j] = __builtin_amdgcn_mfma_f32_16x16x32_bf16(a[i], b[j], acc[i][j], 0, 0, 0);
    }
    int crow0 = (lane >> 4) * 4, ccol = lane & 15;
    #pragma unroll
    for (int i = 0; i < 4; ++i) {
        #pragma unroll
        for (int r = 0; r < 4; ++r) {
            int row = am + i * 16 + crow0 + r;
            int t = row >> 7, b = row & 127;
            #pragma unroll
            for (int j = 0; j < 4; ++j) {
                int col = bn + j * 16 + ccol;
                int g = col >> 9, h = col & 511;
                gx0[((size_t)(t * 3 + g) * 128 + b) * 512 + h] = acc[i][j][r];
            }
        }
    }
}

// ---------------------------------------------------------------- scan
// Flag-array barrier + wave0-ONLY acquire fence (one buffer_inv covers the
// CU's L1 + XCD's L2 for all 8 waves; others gated by the final syncthreads).
__device__ __forceinline__ void grid_bar(int* flags, int gen) {
    __syncthreads();
    if (threadIdx.x == 0)
        __hip_atomic_store(flags + blockIdx.x * 32, gen, __ATOMIC_RELEASE,
                           __HIP_MEMORY_SCOPE_AGENT);
    if (threadIdx.x < NWG) {
        while (__hip_atomic_load(flags + threadIdx.x * 32, __ATOMIC_RELAXED,
                                 __HIP_MEMORY_SCOPE_AGENT) < gen)
            __builtin_amdgcn_s_sleep(1);
    }
    __syncthreads();
    if (threadIdx.x < 64)   // wave 0 only
        __builtin_amdgcn_fence(__ATOMIC_ACQUIRE, "agent");
    __syncthreads();        // others wait for the invalidate
    __builtin_amdgcn_sched_barrier(0);
}

// Persistent scan: 48 WGs x 512 threads (8 waves). Weights LDS-resident.
// wg 0..15  = L0, owns 32 cols/gate (LDS [96][512] bf16, swizzled).
// wg 16..47 = L1, owns 16 cols/gate (LDS [48][1024] bf16, swizzled).
// even slot 2t: L0-P1(t) || L1-P1(t-1);  odd: L0-P2(t) || L1-P2(t-1).
__global__ __launch_bounds__(512) void scan_kernel(
    const float* __restrict__ gx0,
    const float* __restrict__ Wx, const float* __restrict__ Wh,
    const float* __restrict__ bh,
    float* h0f, unsigned short* h0b0, unsigned short* h0b1,
    float* h1f, unsigned short* h1b,
    unsigned short* rh0b, float* f0buf,
    unsigned short* rh1b, float* f1buf,
    unsigned short* h1bf, int* flags, float* hfinal_out) {
    __shared__ unsigned short wlds[96 * 512];   // 96 KB

    const int tid = threadIdx.x;
    const int wg = blockIdx.x;
    const int lane = tid & 63;
    const int wave = tid >> 6;            // 0..7
    const int lr = lane & 15;
    const int hi = lane >> 4;             // 0..3
    const int lk8 = hi * 8;
    const int ccol = lane & 15;
    const int crow0 = hi * 4;
    const int row = wave * 16;            // wave's 16-row slice of B=128

    const bool isL0 = (wg < 16);
    const int wid = wg - 16;

    // ---- one-time LDS weight staging (f32 -> bf16, kg ^= (col&7) swizzle) ----
    if (isL0) {
        for (int i = tid; i < 96 * 64; i += 512) {
            int lc = i >> 6, kg = i & 63;
            int g = lc >> 5, h = (wg << 5) + (lc & 31);
            const float* src = Wh + (size_t)(g * 512 + h) * 512 + kg * 8;
            *(bf16x8*)(wlds + lc * 512 + (kg ^ (lc & 7)) * 8) = cvt8(src);
        }
    } else {
        for (int i = tid; i < 48 * 128; i += 512) {
            int lc = i >> 7, kg = i & 127;
            int g = lc >> 4, h = (wid << 4) + (lc & 15);
            const float* src = (kg < 64)
                ? Wx + (size_t)(g * 512 + h) * 512 + kg * 8
                : Wh + (size_t)(3 * 512 * 512) + (size_t)(g * 512 + h) * 512 + (kg - 64) * 8;
            *(bf16x8*)(wlds + lc * 1024 + (kg ^ (lc & 7)) * 8) = cvt8(src);
        }
    }
    __syncthreads();

    for (int s = 0; s <= 2 * T_ + 1; ++s) {
        int t = s >> 1;
        if ((s & 1) == 0) {
            if (isL0) {
                if (t < T_) {  // ---- L0-P1(t): r,f gates over 64 owned cols
                    const unsigned short* hprev = (t & 1) ? h0b0 : h0b1;
                    bf16x8 a[16];
                    #pragma unroll
                    for (int ks = 0; ks < 16; ++ks)
                        a[ks] = *(const bf16x8*)(hprev + (size_t)(row + lr) * 512 + ks * 32 + lk8);
                    // hoisted epilogue inputs (issue before MFMA chain)
                    float gxv[4][4], h0v[2][4];
                    #pragma unroll
                    for (int j = 0; j < 4; ++j) {
                        int lc = j * 16 + ccol;
                        int g = lc >> 5, h = (wg << 5) + (lc & 31);
                        const float* gx = gx0 + (size_t)(t * 3 + g) * BH_ + h;
                        #pragma unroll
                        for (int r = 0; r < 4; ++r)
                            gxv[j][r] = gx[(row + crow0 + r) * 512];
                    }
                    #pragma unroll
                    for (int j = 0; j < 2; ++j) {
                        int h = (wg << 5) + ((j * 16 + ccol) & 31);
                        #pragma unroll
                        for (int r = 0; r < 4; ++r)
                            h0v[j][r] = h0f[(row + crow0 + r) * 512 + h];
                    }
                    f32x4 acc[4] = {};
                    #pragma unroll
                    for (int ks = 0; ks < 16; ++ks) {
                        int kg = 4 * ks + hi;
                        #pragma unroll
                        for (int j = 0; j < 4; ++j) {
                            int c = j * 16 + lr;
                            bf16x8 b = *(const bf16x8*)(wlds + c * 512 + (kg ^ (c & 7)) * 8);
                            acc[j] = __builtin_amdgcn_mfma_f32_16x16x32_bf16(a[ks], b, acc[j], 0, 0, 0);
                        }
                    }
                    #pragma unroll
                    for (int j = 0; j < 4; ++j) {
                        int lc = j * 16 + ccol;
                        int g = lc >> 5, h = (wg << 5) + (lc & 31);
                        float bias = bh[g * 512 + h];
                        #pragma unroll
                        for (int r = 0; r < 4; ++r) {
                            int b = row + crow0 + r;
                            float v = acc[j][r] + gxv[j][r] + bias;
                            float sg = 1.f / (1.f + __expf(-v));
                            if (g == 0) rh0b[b * 512 + h] = f2bf(sg * h0v[j][r]);
                            else        f0buf[b * 512 + h] = sg;
                        }
                    }
                }
            } else {
                int tc = t - 1;
                if (tc >= 0 && tc < T_) {  // ---- L1-P1(tc): 32 owned cols, K=1024
                    const unsigned short* h0cur = (tc & 1) ? h0b1 : h0b0;
                    bf16x8 a0[16], a1[16];
                    #pragma unroll
                    for (int ks = 0; ks < 16; ++ks) {
                        a0[ks] = *(const bf16x8*)(h0cur + (size_t)(row + lr) * 512 + ks * 32 + lk8);
                        a1[ks] = *(const bf16x8*)(h1b + (size_t)(row + lr) * 512 + ks * 32 + lk8);
                    }
                    float h1v[4];
                    {
                        int h = (wid << 4) + ccol;   // g==0 cols (j==0)
                        #pragma unroll
                        for (int r = 0; r < 4; ++r)
                            h1v[r] = h1f[(row + crow0 + r) * 512 + h];
                    }
                    f32x4 acc[2] = {};
                    #pragma unroll
                    for (int ks = 0; ks < 16; ++ks) {
                        int kg = 4 * ks + hi;
                        #pragma unroll
                        for (int j = 0; j < 2; ++j) {
                            int c = j * 16 + lr;
                            bf16x8 b = *(const bf16x8*)(wlds + c * 1024 + (kg ^ (c & 7)) * 8);
                            acc[j] = __builtin_amdgcn_mfma_f32_16x16x32_bf16(a0[ks], b, acc[j], 0, 0, 0);
                        }
                    }
                    #pragma unroll
                    for (int ks = 0; ks < 16; ++ks) {
                        int kg = 64 + 4 * ks + hi;
                        #pragma unroll
                        for (int j = 0; j < 2; ++j) {
                            int c = j * 16 + lr;
                            bf16x8 b = *(const bf16x8*)(wlds + c * 1024 + (kg ^ (c & 7)) * 8);
                            acc[j] = __builtin_amdgcn_mfma_f32_16x16x32_bf16(a1[ks], b, acc[j], 0, 0, 0);
                        }
                    }
                    #pragma unroll
                    for (int j = 0; j < 2; ++j) {
                        int lc = j * 16 + ccol;
                        int g = lc >> 4, h = (wid << 4) + (lc & 15);
                        float bias = bh[1536 + g * 512 + h];
                        #pragma unroll
                        for (int r = 0; r < 4; ++r) {
                            int b = row + crow0 + r;
                            float v = acc[j][r] + bias;
                            float sg = 1.f / (1.f + __expf(-v));
                            if (g == 0) rh1b[b * 512 + h] = f2bf(sg * h1v[r]);
                            else        f1buf[b * 512 + h] = sg;
                        }
                    }
                }
            }
        } else {
            if (isL0) {
                if (t < T_) {  // ---- L0-P2(t): candidate (32 cols) + blend
                    unsigned short* h0bw = (t & 1) ? h0b1 : h0b0;
                    bf16x8 a[16];
                    #pragma unroll
                    for (int ks = 0; ks < 16; ++ks)
                        a[ks] = *(const bf16x8*)(rh0b + (size_t)(row + lr) * 512 + ks * 32 + lk8);
                    float gxv[2][4], h0v[2][4], fv[2][4];
                    #pragma unroll
                    for (int j = 0; j < 2; ++j) {
                        int h = (wg << 5) + j * 16 + ccol;
                        const float* gx = gx0 + (size_t)(t * 3 + 2) * BH_ + h;
                        #pragma unroll
                        for (int r = 0; r < 4; ++r) {
                            int b = row + crow0 + r;
                            gxv[j][r] = gx[b * 512];
                            h0v[j][r] = h0f[b * 512 + h];
                            fv[j][r]  = f0buf[b * 512 + h];
                        }
                    }
                    f32x4 acc[2] = {};
                    #pragma unroll
                    for (int ks = 0; ks < 16; ++ks) {
                        int kg = 4 * ks + hi;
                        #pragma unroll
                        for (int j = 0; j < 2; ++j) {
                            int c = 64 + j * 16 + lr;
                            bf16x8 b = *(const bf16x8*)(wlds + c * 512 + (kg ^ (c & 7)) * 8);
                            acc[j] = __builtin_amdgcn_mfma_f32_16x16x32_bf16(a[ks], b, acc[j], 0, 0, 0);
                        }
                    }
                    #pragma unroll
                    for (int j = 0; j < 2; ++j) {
                        int h = (wg << 5) + j * 16 + ccol;
                        float bias = bh[1024 + h];
                        #pragma unroll
                        for (int r = 0; r < 4; ++r) {
                            int b = row + crow0 + r;
                            float v = acc[j][r] + gxv[j][r] + bias;
                            float tld = tanhf(v);
                            float hn = h0v[j][r] + fv[j][r] * (tld - h0v[j][r]);
                            h0f[b * 512 + h] = hn;
                            h0bw[b * 512 + h] = f2bf(hn);
                        }
                    }
                }
            } else {
                int tc = t - 1;
                if (tc >= 0 && tc < T_) {  // ---- L1-P2(tc): candidate (16 cols) + blend
                    const unsigned short* h0cur = (tc & 1) ? h0b1 : h0b0;
                    bf16x8 a0[16], a1[16];
                    #pragma unroll
                    for (int ks = 0; ks < 16; ++ks) {
                        a0[ks] = *(const bf16x8*)(h0cur + (size_t)(row + lr) * 512 + ks * 32 + lk8);
                        a1[ks] = *(const bf16x8*)(rh1b + (size_t)(row + lr) * 512 + ks * 32 + lk8);
                    }
                    float h1v[4], fv[4];
                    {
                        int h = (wid << 4) + ccol;
                        #pragma unroll
                        for (int r = 0; r < 4; ++r) {
                            int b = row + crow0 + r;
                            h1v[r] = h1f[b * 512 + h];
                            fv[r]  = f1buf[b * 512 + h];
                        }
                    }
                    f32x4 acc = {0.f, 0.f, 0.f, 0.f};
                    #pragma unroll
                    for (int ks = 0; ks < 16; ++ks) {
                        int kg = 4 * ks + hi;
                        int c = 32 + lr;
                        bf16x8 b = *(const bf16x8*)(wlds + c * 1024 + (kg ^ (c & 7)) * 8);
                        acc = __builtin_amdgcn_mfma_f32_16x16x32_bf16(a0[ks], b, acc, 0, 0, 0);
                    }
                    #pragma unroll
                    for (int ks = 0; ks < 16; ++ks) {
                        int kg = 64 + 4 * ks + hi;
                        int c = 32 + lr;
                        bf16x8 b = *(const bf16x8*)(wlds + c * 1024 + (kg ^ (c & 7)) * 8);
                        acc = __builtin_amdgcn_mfma_f32_16x16x32_bf16(a1[ks], b, acc, 0, 0, 0);
                    }
                    {
                        int h = (wid << 4) + ccol;
                        float bias = bh[2560 + h];
                        #pragma unroll
                        for (int r = 0; r < 4; ++r) {
                            int b = row + crow0 + r;
                            float v = acc[r] + bias;
                            float tld = tanhf(v);
                            float hn = h1v[r] + fv[r] * (tld - h1v[r]);
                            h1f[b * 512 + h] = hn;
                            unsigned short hb = f2bf(hn);
                            h1b[b * 512 + h] = hb;
                            h1bf[(size_t)tc * BH_ + b * 512 + h] = hb;
                        }
                    }
                }
            }
        }
        grid_bar(flags, s + 1);
    }

    // final hidden -> out tail
    for (int i = wg * 512 + tid; i < BH_; i += NWG * 512) {
        hfinal_out[i] = h0f[i];
        hfinal_out[BH_ + i] = h1f[i];
    }
}

// ---------------------------------------------------------------- logits
// C[m][v] = sum_h A[m][h]*Bw[v][h] + bout[v]. A,Bw bf16. Register
// double-buffered k-loop; XCD-chunked n-major block order for B L2 reuse.
#define MT_ (T_ * B_ / 128)          // 35 m-tiles
#define NT_ ((V_ + 127) / 128)       // 79 n-tiles
__global__ __launch_bounds__(256) void logits_gemm(
    const unsigned short* __restrict__ A, const unsigned short* __restrict__ Bw,
    const float* __restrict__ bout, float* __restrict__ C) {
    // bijective XCD swizzle (m204): nwg = MT_*NT_ = 2765, q=345, r=5
    const int nwg = MT_ * NT_;
    const int q = nwg / 8, rr = nwg % 8;
    int bid = blockIdx.x;
    int xcd = bid % 8, idx = bid / 8;
    int wgid = (xcd < rr ? xcd * (q + 1) : rr * (q + 1) + (xcd - rr) * q) + idx;
    int n0 = (wgid / MT_) * 128;
    int m0 = (wgid % MT_) * 128;

    int wave = threadIdx.x >> 6, lane = threadIdx.x & 63;
    int wr = wave >> 1, wc = wave & 1;
    int am = m0 + wr * 64, bn = n0 + wc * 64;
    int lr = lane & 15, lk = (lane >> 4) * 8;

    f32x4 acc[4][4] = {};
    bf16x8 a[4], b[4], an[4], bnx[4];
    #pragma unroll
    for (int i = 0; i < 4; ++i)
        a[i] = *(const bf16x8*)(A + (size_t)(am + i * 16 + lr) * H_ + lk);
    #pragma unroll
    for (int j = 0; j < 4; ++j) {
        int colc = bn + j * 16 + lr; if (colc >= V_) colc = V_ - 1;
        b[j] = *(const bf16x8*)(Bw + (size_t)colc * H_ + lk);
    }
    for (int k0 = 0; k0 < H_; k0 += 32) {
        if (k0 + 32 < H_) {
            #pragma unroll
            for (int i = 0; i < 4; ++i)
                an[i] = *(const bf16x8*)(A + (size_t)(am + i * 16 + lr) * H_ + k0 + 32 + lk);
            #pragma unroll
            for (int j = 0; j < 4; ++j) {
                int colc = bn + j * 16 + lr; if (colc >= V_) colc = V_ - 1;
                bnx[j] = *(const bf16x8*)(Bw + (size_t)colc * H_ + k0 + 32 + lk);
            }
        }
        #pragma unroll
        for (int i = 0; i < 4; ++i)
            #pragma unroll
            for (int j = 0; j < 4; ++j)
                acc[i][j] = __builtin_amdgcn_mfma_f32_16x16x32_bf16(a[i], b[j], acc[i][j], 0, 0, 0);
        #pragma unroll
        for (int i = 0; i < 4; ++i) { a[i] = an[i]; b[i] = bnx[i]; }
    }
    int crow0 = (lane >> 4) * 4, ccol = lane & 15;
    #pragma unroll
    for (int j = 0; j < 4; ++j) {
        int col = bn + j * 16 + ccol;
        if (col >= V_) continue;
        float bv = bout[col];
        #pragma unroll
        for (int i = 0; i < 4; ++i) {
            #pragma unroll
            for (int r = 0; r < 4; ++r) {
                int row = am + i * 16 + crow0 + r;
                __builtin_nontemporal_store(acc[i][j][r] + bv, &C[(size_t)row * V_ + col]);
            }
        }
    }
}

// ---------------------------------------------------------------- launch
extern "C" void kernel_launch(void* const* d_in, const int* in_sizes, int n_in,
                              void* d_out, int out_size, void* d_ws, size_t ws_size,
                              hipStream_t stream) {
    const int*   inputs = (const int*)  d_in[0];
    const float* hidden = (const float*)d_in[1];
    const float* emb    = (const float*)d_in[2];
    const float* Wx0    = (const float*)d_in[3];
    const float* Wx     = (const float*)d_in[4];
    const float* Wh     = (const float*)d_in[5];
    const float* bh     = (const float*)d_in[6];
    const float* Wout   = (const float*)d_in[7];
    const float* bout   = (const float*)d_in[8];
    float* out = (float*)d_out;
    (void)in_sizes; (void)n_in; (void)out_size; (void)ws_size;

    char* ws = (char*)d_ws;
    size_t off = 0;
    auto alloc = [&](size_t bytes) -> void* {
        void* p = ws + off;
        off += (bytes + 255) & ~(size_t)255;
        return p;
    };
    unsigned short* embB   = (unsigned short*)alloc((size_t)V_ * KPAD * 2);
    unsigned short* wx0cat = (unsigned short*)alloc((size_t)1536 * KPAD * 2);
    unsigned short* WoutB  = (unsigned short*)alloc((size_t)V_ * H_ * 2);
    unsigned short* h1bf   = (unsigned short*)alloc((size_t)T_ * BH_ * 2);
    float* h0f  = (float*)alloc(BH_ * 4);
    float* h1f  = (float*)alloc(BH_ * 4);
    unsigned short* h0b0 = (unsigned short*)alloc(BH_ * 2);
    unsigned short* h0b1 = (unsigned short*)alloc(BH_ * 2);
    unsigned short* h1b  = (unsigned short*)alloc(BH_ * 2);
    unsigned short* rh0b = (unsigned short*)alloc(BH_ * 2);
    unsigned short* rh1b = (unsigned short*)alloc(BH_ * 2);
    float* f0buf = (float*)alloc(BH_ * 4);
    float* f1buf = (float*)alloc(BH_ * 4);
    int* flags = (int*)alloc(NWG * 32 * 4);

    // gx0 [T][3][128][512] f32 lives in d_out; overwritten by logits later.
    float* gx0 = out;

    prep_all<<<dim3(1024, 4), dim3(256), 0, stream>>>(
        emb, Wx0, hidden, Wout, embB, wx0cat, WoutB, h0f, h0b1, h1f, h1b, flags);
    xside_gemm<<<dim3(T_, 12), dim3(256), 0, stream>>>(inputs, embB, wx0cat, gx0);
    scan_kernel<<<dim3(NWG), dim3(512), 0, stream>>>(
        gx0, Wx, Wh, bh,
        h0f, h0b0, h0b1, h1f, h1b, rh0b, f0buf, rh1b, f1buf, h1bf, flags,
        out + (size_t)T_ * B_ * V_);
    logits_gemm<<<dim3(MT_ * NT_), dim3(256), 0, stream>>>(h1bf, WoutB, bout, out);
}

// Round 10
// 903.770 us; speedup vs baseline: 3.2233x; 1.0691x over previous
//
#include <hip/hip_runtime.h>
#include <hip/hip_bf16.h>

#define T_ 35
#define B_ 128
#define E_ 200
#define H_ 512
#define L_ 2
#define V_ 10000
#define BH_ (B_ * H_)
#define KPAD 224
#define NWG 48

typedef __attribute__((ext_vector_type(8))) short bf16x8;
typedef __attribute__((ext_vector_type(4))) float f32x4;

__device__ __forceinline__ unsigned short f2bf(float f) {
    union { float f; unsigned u; } c; c.f = f;
    unsigned r = c.u + 0x7FFF + ((c.u >> 16) & 1);
    return (unsigned short)(r >> 16);
}

__device__ __forceinline__ bf16x8 cvt8(const float* src) {
    float4 w0 = *(const float4*)src;
    float4 w1 = *(const float4*)(src + 4);
    bf16x8 v;
    v[0] = (short)f2bf(w0.x); v[1] = (short)f2bf(w0.y);
    v[2] = (short)f2bf(w0.z); v[3] = (short)f2bf(w0.w);
    v[4] = (short)f2bf(w1.x); v[5] = (short)f2bf(w1.y);
    v[6] = (short)f2bf(w1.z); v[7] = (short)f2bf(w1.w);
    return v;
}

// ---------------------------------------------------------------- prep
// job 0: embB bf16; job 1: wx0cat bf16; job 2: bf16 state init + flags; job 3: WoutB
__global__ void prep_all(const float* __restrict__ emb, const float* __restrict__ Wx0,
                         const float* __restrict__ hidden, const float* __restrict__ Wout,
                         unsigned short* embB, unsigned short* wx0cat,
                         unsigned short* WoutB,
                         unsigned short* h0b1, unsigned short* h1b, int* flags) {
    int job = blockIdx.y;
    int stride = gridDim.x * blockDim.x;
    int i0 = blockIdx.x * blockDim.x + threadIdx.x;
    if (job == 0) {
        for (int i = i0; i < V_ * KPAD; i += stride) {
            int v = i / KPAD, k = i - v * KPAD;
            embB[i] = (k < E_) ? f2bf(emb[v * E_ + k]) : (unsigned short)0;
        }
    } else if (job == 1) {
        for (int i = i0; i < 1536 * KPAD; i += stride) {
            int n = i / KPAD, k = i - n * KPAD;
            wx0cat[i] = (k < E_) ? f2bf(Wx0[n * E_ + k]) : (unsigned short)0;
        }
    } else if (job == 2) {
        for (int i = i0; i < 2 * BH_; i += stride) {
            if (i < BH_) h0b1[i] = f2bf(hidden[i]);
            else         h1b[i - BH_] = f2bf(hidden[i]);
        }
        for (int i = i0; i < NWG * 32; i += stride) flags[i] = 0;
    } else {
        for (int i = i0; i < V_ * H_; i += stride) WoutB[i] = f2bf(Wout[i]);
    }
}

// ---------------------------------------------------------------- x-side GEMM
__global__ __launch_bounds__(256) void xside_gemm(
    const int* __restrict__ inputs, const unsigned short* __restrict__ embB,
    const unsigned short* __restrict__ wx0cat, float* __restrict__ gx0) {
    int m0 = blockIdx.x * 128, n0 = blockIdx.y * 128;
    int wave = threadIdx.x >> 6, lane = threadIdx.x & 63;
    int wr = wave >> 1, wc = wave & 1;
    int am = m0 + wr * 64, bn = n0 + wc * 64;
    int lr = lane & 15, lk = (lane >> 4) * 8;

    f32x4 acc[4][4] = {};
    int id[4];
    #pragma unroll
    for (int i = 0; i < 4; ++i) id[i] = inputs[am + i * 16 + lr];

    for (int k0 = 0; k0 < KPAD; k0 += 32) {
        bf16x8 a[4], b[4];
        #pragma unroll
        for (int i = 0; i < 4; ++i)
            a[i] = *(const bf16x8*)(embB + (size_t)id[i] * KPAD + k0 + lk);
        #pragma unroll
        for (int j = 0; j < 4; ++j)
            b[j] = *(const bf16x8*)(wx0cat + (size_t)(bn + j * 16 + lr) * KPAD + k0 + lk);
        #pragma unroll
        for (int i = 0; i < 4; ++i)
            #pragma unroll
            for (int j = 0; j < 4; ++j)
                acc[i][j] = __builtin_amdgcn_mfma_f32_16x16x32_bf16(a[i], b[j], acc[i][j], 0, 0, 0);
    }
    int crow0 = (lane >> 4) * 4, ccol = lane & 15;
    #pragma unroll
    for (int i = 0; i < 4; ++i) {
        #pragma unroll
        for (int r = 0; r < 4; ++r) {
            int row = am + i * 16 + crow0 + r;
            int t = row >> 7, b = row & 127;
            #pragma unroll
            for (int j = 0; j < 4; ++j) {
                int col = bn + j * 16 + ccol;
                int g = col >> 9, h = col & 511;
                gx0[((size_t)(t * 3 + g) * 128 + b) * 512 + h] = acc[i][j][r];
            }
        }
    }
}

// ---------------------------------------------------------------- scan
// Flag-array barrier + wave0-only acquire fence (one L1/L2 inv per WG per slot).
__device__ __forceinline__ void grid_bar(int* flags, int gen) {
    __syncthreads();
    if (threadIdx.x == 0)
        __hip_atomic_store(flags + blockIdx.x * 32, gen, __ATOMIC_RELEASE,
                           __HIP_MEMORY_SCOPE_AGENT);
    if (threadIdx.x < NWG) {
        while (__hip_atomic_load(flags + threadIdx.x * 32, __ATOMIC_RELAXED,
                                 __HIP_MEMORY_SCOPE_AGENT) < gen)
            __builtin_amdgcn_s_sleep(1);
    }
    __syncthreads();
    if (threadIdx.x < 64)
        __builtin_amdgcn_fence(__ATOMIC_ACQUIRE, "agent");
    __syncthreads();
    __builtin_amdgcn_sched_barrier(0);
}

// Persistent scan: 48 WGs x 512 threads. Weights LDS-resident; f32 hidden
// state + forget gates + biases REGISTER-resident (producer==consumer lane).
// Memory carries only cross-WG bf16 operands (h0b parity, h1b, rh0b, rh1b, h1bf).
__global__ __launch_bounds__(512) void scan_kernel(
    const float* __restrict__ gx0,
    const float* __restrict__ Wx, const float* __restrict__ Wh,
    const float* __restrict__ bh, const float* __restrict__ hidden,
    unsigned short* h0b0, unsigned short* h0b1,
    unsigned short* h1b,
    unsigned short* rh0b, unsigned short* rh1b,
    unsigned short* h1bf, int* flags, float* hfinal_out) {
    __shared__ unsigned short wlds[96 * 512];   // 96 KB

    const int tid = threadIdx.x;
    const int wg = blockIdx.x;
    const int lane = tid & 63;
    const int wave = tid >> 6;            // 0..7
    const int lr = lane & 15;
    const int hi = lane >> 4;             // 0..3
    const int lk8 = hi * 8;
    const int ccol = lane & 15;
    const int crow0 = hi * 4;
    const int row = wave * 16;            // wave's 16-row slice of B=128

    const bool isL0 = (wg < 16);
    const int wid = wg - 16;

    // ---- one-time LDS weight staging (f32 -> bf16, kg ^= (col&7) swizzle) ----
    if (isL0) {
        for (int i = tid; i < 96 * 64; i += 512) {
            int lc = i >> 6, kg = i & 63;
            int g = lc >> 5, h = (wg << 5) + (lc & 31);
            const float* src = Wh + (size_t)(g * 512 + h) * 512 + kg * 8;
            *(bf16x8*)(wlds + lc * 512 + (kg ^ (lc & 7)) * 8) = cvt8(src);
        }
    } else {
        for (int i = tid; i < 48 * 128; i += 512) {
            int lc = i >> 7, kg = i & 127;
            int g = lc >> 4, h = (wid << 4) + (lc & 15);
            const float* src = (kg < 64)
                ? Wx + (size_t)(g * 512 + h) * 512 + kg * 8
                : Wh + (size_t)(3 * 512 * 512) + (size_t)(g * 512 + h) * 512 + (kg - 64) * 8;
            *(bf16x8*)(wlds + lc * 1024 + (kg ^ (lc & 7)) * 8) = cvt8(src);
        }
    }

    // ---- register-resident state, gates, biases ----
    float h0reg[2][4], freg0[2][4], bias_p1_0[4], bias_p2_0[2];
    float h1reg[4], freg1[4], bias_p1_1[2], bias_p2_1;
    if (isL0) {
        const int base = wg << 5;
        #pragma unroll
        for (int j = 0; j < 2; ++j)
            #pragma unroll
            for (int r = 0; r < 4; ++r)
                h0reg[j][r] = hidden[(size_t)(row + crow0 + r) * 512 + base + j * 16 + ccol];
        #pragma unroll
        for (int j = 0; j < 4; ++j) {
            int lc = j * 16 + ccol;
            bias_p1_0[j] = bh[(lc >> 5) * 512 + base + (lc & 31)];
        }
        #pragma unroll
        for (int j = 0; j < 2; ++j)
            bias_p2_0[j] = bh[1024 + base + j * 16 + ccol];
    } else {
        const int base = wid << 4;
        #pragma unroll
        for (int r = 0; r < 4; ++r)
            h1reg[r] = hidden[(size_t)BH_ + (size_t)(row + crow0 + r) * 512 + base + ccol];
        bias_p1_1[0] = bh[1536 + base + ccol];
        bias_p1_1[1] = bh[1536 + 512 + base + ccol];
        bias_p2_1 = bh[2560 + base + ccol];
    }
    __syncthreads();

    for (int s = 0; s <= 2 * T_ + 1; ++s) {
        int t = s >> 1;
        if ((s & 1) == 0) {
            if (isL0) {
                if (t < T_) {  // ---- L0-P1(t): r,f gates over 64 owned cols
                    const int base = wg << 5;
                    const unsigned short* hprev = (t & 1) ? h0b0 : h0b1;
                    bf16x8 a[16];
                    #pragma unroll
                    for (int ks = 0; ks < 16; ++ks)
                        a[ks] = *(const bf16x8*)(hprev + (size_t)(row + lr) * 512 + ks * 32 + lk8);
                    float gxv[4][4];
                    #pragma unroll
                    for (int j = 0; j < 4; ++j) {
                        int lc = j * 16 + ccol;
                        const float* gx = gx0 + (size_t)(t * 3 + (lc >> 5)) * BH_ + base + (lc & 31);
                        #pragma unroll
                        for (int r = 0; r < 4; ++r)
                            gxv[j][r] = gx[(row + crow0 + r) * 512];
                    }
                    f32x4 acc[4] = {};
                    #pragma unroll
                    for (int ks = 0; ks < 16; ++ks) {
                        int kg = 4 * ks + hi;
                        #pragma unroll
                        for (int j = 0; j < 4; ++j) {
                            int c = j * 16 + lr;
                            bf16x8 b = *(const bf16x8*)(wlds + c * 512 + (kg ^ (c & 7)) * 8);
                            acc[j] = __builtin_amdgcn_mfma_f32_16x16x32_bf16(a[ks], b, acc[j], 0, 0, 0);
                        }
                    }
                    #pragma unroll
                    for (int j = 0; j < 4; ++j) {
                        int h = base + ((j & 1) * 16) + ccol;
                        #pragma unroll
                        for (int r = 0; r < 4; ++r) {
                            int b = row + crow0 + r;
                            float v = acc[j][r] + gxv[j][r] + bias_p1_0[j];
                            float sg = 1.f / (1.f + __expf(-v));
                            if (j < 2) rh0b[b * 512 + h] = f2bf(sg * h0reg[j][r]);
                            else       freg0[j - 2][r] = sg;
                        }
                    }
                }
            } else {
                int tc = t - 1;
                if (tc >= 0 && tc < T_) {  // ---- L1-P1(tc): 32 owned cols, K=1024
                    const int base = wid << 4;
                    const unsigned short* h0cur = (tc & 1) ? h0b1 : h0b0;
                    bf16x8 a0[16], a1[16];
                    #pragma unroll
                    for (int ks = 0; ks < 16; ++ks) {
                        a0[ks] = *(const bf16x8*)(h0cur + (size_t)(row + lr) * 512 + ks * 32 + lk8);
                        a1[ks] = *(const bf16x8*)(h1b + (size_t)(row + lr) * 512 + ks * 32 + lk8);
                    }
                    f32x4 acc[2] = {};
                    #pragma unroll
                    for (int ks = 0; ks < 16; ++ks) {
                        int kg = 4 * ks + hi;
                        #pragma unroll
                        for (int j = 0; j < 2; ++j) {
                            int c = j * 16 + lr;
                            bf16x8 b = *(const bf16x8*)(wlds + c * 1024 + (kg ^ (c & 7)) * 8);
                            acc[j] = __builtin_amdgcn_mfma_f32_16x16x32_bf16(a0[ks], b, acc[j], 0, 0, 0);
                        }
                    }
                    #pragma unroll
                    for (int ks = 0; ks < 16; ++ks) {
                        int kg = 64 + 4 * ks + hi;
                        #pragma unroll
                        for (int j = 0; j < 2; ++j) {
                            int c = j * 16 + lr;
                            bf16x8 b = *(const bf16x8*)(wlds + c * 1024 + (kg ^ (c & 7)) * 8);
                            acc[j] = __builtin_amdgcn_mfma_f32_16x16x32_bf16(a1[ks], b, acc[j], 0, 0, 0);
                        }
                    }
                    #pragma unroll
                    for (int j = 0; j < 2; ++j) {
                        int h = base + ccol;
                        #pragma unroll
                        for (int r = 0; r < 4; ++r) {
                            int b = row + crow0 + r;
                            float v = acc[j][r] + bias_p1_1[j];
                            float sg = 1.f / (1.f + __expf(-v));
                            if (j == 0) rh1b[b * 512 + h] = f2bf(sg * h1reg[r]);
                            else        freg1[r] = sg;
                        }
                    }
                }
            }
        } else {
            if (isL0) {
                if (t < T_) {  // ---- L0-P2(t): candidate (32 cols) + blend
                    const int base = wg << 5;
                    unsigned short* h0bw = (t & 1) ? h0b1 : h0b0;
                    bf16x8 a[16];
                    #pragma unroll
                    for (int ks = 0; ks < 16; ++ks)
                        a[ks] = *(const bf16x8*)(rh0b + (size_t)(row + lr) * 512 + ks * 32 + lk8);
                    float gxv[2][4];
                    #pragma unroll
                    for (int j = 0; j < 2; ++j) {
                        const float* gx = gx0 + (size_t)(t * 3 + 2) * BH_ + base + j * 16 + ccol;
                        #pragma unroll
                        for (int r = 0; r < 4; ++r)
                            gxv[j][r] = gx[(row + crow0 + r) * 512];
                    }
                    f32x4 acc[2] = {};
                    #pragma unroll
                    for (int ks = 0; ks < 16; ++ks) {
                        int kg = 4 * ks + hi;
                        #pragma unroll
                        for (int j = 0; j < 2; ++j) {
                            int c = 64 + j * 16 + lr;
                            bf16x8 b = *(const bf16x8*)(wlds + c * 512 + (kg ^ (c & 7)) * 8);
                            acc[j] = __builtin_amdgcn_mfma_f32_16x16x32_bf16(a[ks], b, acc[j], 0, 0, 0);
                        }
                    }
                    #pragma unroll
                    for (int j = 0; j < 2; ++j) {
                        int h = base + j * 16 + ccol;
                        #pragma unroll
                        for (int r = 0; r < 4; ++r) {
                            int b = row + crow0 + r;
                            float v = acc[j][r] + gxv[j][r] + bias_p2_0[j];
                            float tld = tanhf(v);
                            float hn = h0reg[j][r] + freg0[j][r] * (tld - h0reg[j][r]);
                            h0reg[j][r] = hn;
                            h0bw[b * 512 + h] = f2bf(hn);
                        }
                    }
                }
            } else {
                int tc = t - 1;
                if (tc >= 0 && tc < T_) {  // ---- L1-P2(tc): candidate (16 cols) + blend
                    const int base = wid << 4;
                    const unsigned short* h0cur = (tc & 1) ? h0b1 : h0b0;
                    bf16x8 a0[16], a1[16];
                    #pragma unroll
                    for (int ks = 0; ks < 16; ++ks) {
                        a0[ks] = *(const bf16x8*)(h0cur + (size_t)(row + lr) * 512 + ks * 32 + lk8);
                        a1[ks] = *(const bf16x8*)(rh1b + (size_t)(row + lr) * 512 + ks * 32 + lk8);
                    }
                    f32x4 acc = {0.f, 0.f, 0.f, 0.f};
                    #pragma unroll
                    for (int ks = 0; ks < 16; ++ks) {
                        int kg = 4 * ks + hi;
                        int c = 32 + lr;
                        bf16x8 b = *(const bf16x8*)(wlds + c * 1024 + (kg ^ (c & 7)) * 8);
                        acc = __builtin_amdgcn_mfma_f32_16x16x32_bf16(a0[ks], b, acc, 0, 0, 0);
                    }
                    #pragma unroll
                    for (int ks = 0; ks < 16; ++ks) {
                        int kg = 64 + 4 * ks + hi;
                        int c = 32 + lr;
                        bf16x8 b = *(const bf16x8*)(wlds + c * 1024 + (kg ^ (c & 7)) * 8);
                        acc = __builtin_amdgcn_mfma_f32_16x16x32_bf16(a1[ks], b, acc, 0, 0, 0);
                    }
                    {
                        int h = base + ccol;
                        #pragma unroll
                        for (int r = 0; r < 4; ++r) {
                            int b = row + crow0 + r;
                            float v = acc[r] + bias_p2_1;
                            float tld = tanhf(v);
                            float hn = h1reg[r] + freg1[r] * (tld - h1reg[r]);
                            h1reg[r] = hn;
                            unsigned short hb = f2bf(hn);
                            h1b[b * 512 + h] = hb;
                            h1bf[(size_t)tc * BH_ + b * 512 + h] = hb;
                        }
                    }
                }
            }
        }
        grid_bar(flags, s + 1);
    }

    // final hidden from registers (each lane owns its elements)
    if (isL0) {
        const int base = wg << 5;
        #pragma unroll
        for (int j = 0; j < 2; ++j)
            #pragma unroll
            for (int r = 0; r < 4; ++r)
                hfinal_out[(size_t)(row + crow0 + r) * 512 + base + j * 16 + ccol] = h0reg[j][r];
    } else {
        const int base = wid << 4;
        #pragma unroll
        for (int r = 0; r < 4; ++r)
            hfinal_out[(size_t)BH_ + (size_t)(row + crow0 + r) * 512 + base + ccol] = h1reg[r];
    }
}

// ---------------------------------------------------------------- logits
#define MT_ (T_ * B_ / 128)          // 35 m-tiles
#define NT_ ((V_ + 127) / 128)       // 79 n-tiles
__global__ __launch_bounds__(256) void logits_gemm(
    const unsigned short* __restrict__ A, const unsigned short* __restrict__ Bw,
    const float* __restrict__ bout, float* __restrict__ C) {
    const int nwg = MT_ * NT_;
    const int q = nwg / 8, rr = nwg % 8;
    int bid = blockIdx.x;
    int xcd = bid % 8, idx = bid / 8;
    int wgid = (xcd < rr ? xcd * (q + 1) : rr * (q + 1) + (xcd - rr) * q) + idx;
    int n0 = (wgid / MT_) * 128;
    int m0 = (wgid % MT_) * 128;

    int wave = threadIdx.x >> 6, lane = threadIdx.x & 63;
    int wr = wave >> 1, wc = wave & 1;
    int am = m0 + wr * 64, bn = n0 + wc * 64;
    int lr = lane & 15, lk = (lane >> 4) * 8;

    f32x4 acc[4][4] = {};
    bf16x8 a[4], b[4], an[4], bnx[4];
    #pragma unroll
    for (int i = 0; i < 4; ++i)
        a[i] = *(const bf16x8*)(A + (size_t)(am + i * 16 + lr) * H_ + lk);
    #pragma unroll
    for (int j = 0; j < 4; ++j) {
        int colc = bn + j * 16 + lr; if (colc >= V_) colc = V_ - 1;
        b[j] = *(const bf16x8*)(Bw + (size_t)colc * H_ + lk);
    }
    for (int k0 = 0; k0 < H_; k0 += 32) {
        if (k0 + 32 < H_) {
            #pragma unroll
            for (int i = 0; i < 4; ++i)
                an[i] = *(const bf16x8*)(A + (size_t)(am + i * 16 + lr) * H_ + k0 + 32 + lk);
            #pragma unroll
            for (int j = 0; j < 4; ++j) {
                int colc = bn + j * 16 + lr; if (colc >= V_) colc = V_ - 1;
                bnx[j] = *(const bf16x8*)(Bw + (size_t)colc * H_ + k0 + 32 + lk);
            }
        }
        #pragma unroll
        for (int i = 0; i < 4; ++i)
            #pragma unroll
            for (int j = 0; j < 4; ++j)
                acc[i][j] = __builtin_amdgcn_mfma_f32_16x16x32_bf16(a[i], b[j], acc[i][j], 0, 0, 0);
        #pragma unroll
        for (int i = 0; i < 4; ++i) { a[i] = an[i]; b[i] = bnx[i]; }
    }
    int crow0 = (lane >> 4) * 4, ccol = lane & 15;
    #pragma unroll
    for (int j = 0; j < 4; ++j) {
        int col = bn + j * 16 + ccol;
        if (col >= V_) continue;
        float bv = bout[col];
        #pragma unroll
        for (int i = 0; i < 4; ++i) {
            #pragma unroll
            for (int r = 0; r < 4; ++r) {
                int row = am + i * 16 + crow0 + r;
                __builtin_nontemporal_store(acc[i][j][r] + bv, &C[(size_t)row * V_ + col]);
            }
        }
    }
}

// ---------------------------------------------------------------- launch
extern "C" void kernel_launch(void* const* d_in, const int* in_sizes, int n_in,
                              void* d_out, int out_size, void* d_ws, size_t ws_size,
                              hipStream_t stream) {
    const int*   inputs = (const int*)  d_in[0];
    const float* hidden = (const float*)d_in[1];
    const float* emb    = (const float*)d_in[2];
    const float* Wx0    = (const float*)d_in[3];
    const float* Wx     = (const float*)d_in[4];
    const float* Wh     = (const float*)d_in[5];
    const float* bh     = (const float*)d_in[6];
    const float* Wout   = (const float*)d_in[7];
    const float* bout   = (const float*)d_in[8];
    float* out = (float*)d_out;
    (void)in_sizes; (void)n_in; (void)out_size; (void)ws_size;

    char* ws = (char*)d_ws;
    size_t off = 0;
    auto alloc = [&](size_t bytes) -> void* {
        void* p = ws + off;
        off += (bytes + 255) & ~(size_t)255;
        return p;
    };
    unsigned short* embB   = (unsigned short*)alloc((size_t)V_ * KPAD * 2);
    unsigned short* wx0cat = (unsigned short*)alloc((size_t)1536 * KPAD * 2);
    unsigned short* WoutB  = (unsigned short*)alloc((size_t)V_ * H_ * 2);
    unsigned short* h1bf   = (unsigned short*)alloc((size_t)T_ * BH_ * 2);
    unsigned short* h0b0 = (unsigned short*)alloc(BH_ * 2);
    unsigned short* h0b1 = (unsigned short*)alloc(BH_ * 2);
    unsigned short* h1b  = (unsigned short*)alloc(BH_ * 2);
    unsigned short* rh0b = (unsigned short*)alloc(BH_ * 2);
    unsigned short* rh1b = (unsigned short*)alloc(BH_ * 2);
    int* flags = (int*)alloc(NWG * 32 * 4);

    // gx0 [T][3][128][512] f32 lives in d_out; overwritten by logits later.
    float* gx0 = out;

    prep_all<<<dim3(1024, 4), dim3(256), 0, stream>>>(
        emb, Wx0, hidden, Wout, embB, wx0cat, WoutB, h0b1, h1b, flags);
    xside_gemm<<<dim3(T_, 12), dim3(256), 0, stream>>>(inputs, embB, wx0cat, gx0);
    scan_kernel<<<dim3(NWG), dim3(512), 0, stream>>>(
        gx0, Wx, Wh, bh, hidden,
        h0b0, h0b1, h1b, rh0b, rh1b, h1bf, flags,
        out + (size_t)T_ * B_ * V_);
    logits_gemm<<<dim3(MT_ * NT_), dim3(256), 0, stream>>>(h1bf, WoutB, bout, out);
}

// Round 11
// 809.565 us; speedup vs baseline: 3.5984x; 1.1164x over previous
//
#include <hip/hip_runtime.h>
#include <hip/hip_bf16.h>

#define T_ 35
#define B_ 128
#define E_ 200
#define H_ 512
#define L_ 2
#define V_ 10000
#define BH_ (B_ * H_)
#define KPAD 224
#define NWG 48

typedef __attribute__((ext_vector_type(8))) short bf16x8;
typedef __attribute__((ext_vector_type(4))) float f32x4;

__device__ __forceinline__ unsigned short f2bf(float f) {
    union { float f; unsigned u; } c; c.f = f;
    unsigned r = c.u + 0x7FFF + ((c.u >> 16) & 1);
    return (unsigned short)(r >> 16);
}

__device__ __forceinline__ bf16x8 cvt8(const float* src) {
    float4 w0 = *(const float4*)src;
    float4 w1 = *(const float4*)(src + 4);
    bf16x8 v;
    v[0] = (short)f2bf(w0.x); v[1] = (short)f2bf(w0.y);
    v[2] = (short)f2bf(w0.z); v[3] = (short)f2bf(w0.w);
    v[4] = (short)f2bf(w1.x); v[5] = (short)f2bf(w1.y);
    v[6] = (short)f2bf(w1.z); v[7] = (short)f2bf(w1.w);
    return v;
}

// pair-pack bf16 -> one 4B relaxed agent-scope store (bypasses to coherence
// point; r5-proven visible cross-XCD). idx must be even on even lanes.
__device__ __forceinline__ void store_pair_bf16(unsigned short* buf, int idx,
                                                float v, int lane) {
    float vn = __shfl_xor(v, 1);
    if ((lane & 1) == 0) {
        unsigned p = (unsigned)f2bf(v) | ((unsigned)f2bf(vn) << 16);
        __hip_atomic_store((unsigned*)(buf + idx), p,
                           __ATOMIC_RELAXED, __HIP_MEMORY_SCOPE_AGENT);
    }
}

// ---------------------------------------------------------------- prep
// job 0: embB bf16; job 1: wx0cat bf16; job 2: init state slots + flags; job 3: WoutB
__global__ void prep_all(const float* __restrict__ emb, const float* __restrict__ Wx0,
                         const float* __restrict__ hidden, const float* __restrict__ Wout,
                         unsigned short* embB, unsigned short* wx0cat,
                         unsigned short* WoutB,
                         unsigned short* h0bt, unsigned short* h1bfx, int* flags) {
    int job = blockIdx.y;
    int stride = gridDim.x * blockDim.x;
    int i0 = blockIdx.x * blockDim.x + threadIdx.x;
    if (job == 0) {
        for (int i = i0; i < V_ * KPAD; i += stride) {
            int v = i / KPAD, k = i - v * KPAD;
            embB[i] = (k < E_) ? f2bf(emb[v * E_ + k]) : (unsigned short)0;
        }
    } else if (job == 1) {
        for (int i = i0; i < 1536 * KPAD; i += stride) {
            int n = i / KPAD, k = i - n * KPAD;
            wx0cat[i] = (k < E_) ? f2bf(Wx0[n * E_ + k]) : (unsigned short)0;
        }
    } else if (job == 2) {
        for (int i = i0; i < 2 * BH_; i += stride) {
            if (i < BH_) h0bt[i] = f2bf(hidden[i]);           // h0bt[0] = init
            else         h1bfx[i - BH_] = f2bf(hidden[i]);    // h1bfx[0] = init
        }
        for (int i = i0; i < NWG * 32; i += stride) flags[i] = 0;
    } else {
        for (int i = i0; i < V_ * H_; i += stride) WoutB[i] = f2bf(Wout[i]);
    }
}

// ---------------------------------------------------------------- x-side GEMM
__global__ __launch_bounds__(256) void xside_gemm(
    const int* __restrict__ inputs, const unsigned short* __restrict__ embB,
    const unsigned short* __restrict__ wx0cat, float* __restrict__ gx0) {
    int m0 = blockIdx.x * 128, n0 = blockIdx.y * 128;
    int wave = threadIdx.x >> 6, lane = threadIdx.x & 63;
    int wr = wave >> 1, wc = wave & 1;
    int am = m0 + wr * 64, bn = n0 + wc * 64;
    int lr = lane & 15, lk = (lane >> 4) * 8;

    f32x4 acc[4][4] = {};
    int id[4];
    #pragma unroll
    for (int i = 0; i < 4; ++i) id[i] = inputs[am + i * 16 + lr];

    for (int k0 = 0; k0 < KPAD; k0 += 32) {
        bf16x8 a[4], b[4];
        #pragma unroll
        for (int i = 0; i < 4; ++i)
            a[i] = *(const bf16x8*)(embB + (size_t)id[i] * KPAD + k0 + lk);
        #pragma unroll
        for (int j = 0; j < 4; ++j)
            b[j] = *(const bf16x8*)(wx0cat + (size_t)(bn + j * 16 + lr) * KPAD + k0 + lk);
        #pragma unroll
        for (int i = 0; i < 4; ++i)
            #pragma unroll
            for (int j = 0; j < 4; ++j)
                acc[i][j] = __builtin_amdgcn_mfma_f32_16x16x32_bf16(a[i], b[j], acc[i][j], 0, 0, 0);
    }
    int crow0 = (lane >> 4) * 4, ccol = lane & 15;
    #pragma unroll
    for (int i = 0; i < 4; ++i) {
        #pragma unroll
        for (int r = 0; r < 4; ++r) {
            int row = am + i * 16 + crow0 + r;
            int t = row >> 7, b = row & 127;
            #pragma unroll
            for (int j = 0; j < 4; ++j) {
                int col = bn + j * 16 + ccol;
                int g = col >> 9, h = col & 511;
                gx0[((size_t)(t * 3 + g) * 128 + b) * 512 + h] = acc[i][j][r];
            }
        }
    }
}

// ---------------------------------------------------------------- scan
// Fence-free barrier: __syncthreads drains vmcnt(0) (bypass stores acked at
// coherence point) -> relaxed flag store -> relaxed poll. No wbL2/inv ever:
// communicated buffers are per-timestep rotated (never cached before their
// single-reader slot), so normal cached consumer loads cold-miss to MALL.
__device__ __forceinline__ void grid_bar(int* flags, int gen) {
    __syncthreads();
    if (threadIdx.x == 0)
        __hip_atomic_store(flags + blockIdx.x * 32, gen,
                           __ATOMIC_RELAXED, __HIP_MEMORY_SCOPE_AGENT);
    if (threadIdx.x < NWG) {
        while (__hip_atomic_load(flags + threadIdx.x * 32, __ATOMIC_RELAXED,
                                 __HIP_MEMORY_SCOPE_AGENT) < gen)
            __builtin_amdgcn_s_sleep(1);
    }
    __syncthreads();
}

// Persistent scan: 48 WGs x 512 threads. Weights LDS-resident; f32 state +
// forget gates + biases register-resident. Cross-WG comms via rotated bf16
// buffers: h0bt[36], rh0t[35], rh1t[35], h1bfx[36] (each written slot s,
// read slot s+1/s+2 only).
__global__ __launch_bounds__(512) void scan_kernel(
    const float* __restrict__ gx0,
    const float* __restrict__ Wx, const float* __restrict__ Wh,
    const float* __restrict__ bh, const float* __restrict__ hidden,
    unsigned short* h0bt, unsigned short* rh0t, unsigned short* rh1t,
    unsigned short* h1bfx, int* flags, float* hfinal_out) {
    __shared__ unsigned short wlds[96 * 512];   // 96 KB

    const int tid = threadIdx.x;
    const int wg = blockIdx.x;
    const int lane = tid & 63;
    const int wave = tid >> 6;            // 0..7
    const int lr = lane & 15;
    const int hi = lane >> 4;             // 0..3
    const int lk8 = hi * 8;
    const int ccol = lane & 15;
    const int crow0 = hi * 4;
    const int row = wave * 16;            // wave's 16-row slice of B=128

    const bool isL0 = (wg < 16);
    const int wid = wg - 16;

    // ---- one-time LDS weight staging (f32 -> bf16, kg ^= (col&7) swizzle) ----
    if (isL0) {
        for (int i = tid; i < 96 * 64; i += 512) {
            int lc = i >> 6, kg = i & 63;
            int g = lc >> 5, h = (wg << 5) + (lc & 31);
            const float* src = Wh + (size_t)(g * 512 + h) * 512 + kg * 8;
            *(bf16x8*)(wlds + lc * 512 + (kg ^ (lc & 7)) * 8) = cvt8(src);
        }
    } else {
        for (int i = tid; i < 48 * 128; i += 512) {
            int lc = i >> 7, kg = i & 127;
            int g = lc >> 4, h = (wid << 4) + (lc & 15);
            const float* src = (kg < 64)
                ? Wx + (size_t)(g * 512 + h) * 512 + kg * 8
                : Wh + (size_t)(3 * 512 * 512) + (size_t)(g * 512 + h) * 512 + (kg - 64) * 8;
            *(bf16x8*)(wlds + lc * 1024 + (kg ^ (lc & 7)) * 8) = cvt8(src);
        }
    }

    // ---- register-resident state, gates, biases ----
    float h0reg[2][4], freg0[2][4], bias_p1_0[4], bias_p2_0[2];
    float h1reg[4], freg1[4], bias_p1_1[2], bias_p2_1;
    if (isL0) {
        const int base = wg << 5;
        #pragma unroll
        for (int j = 0; j < 2; ++j)
            #pragma unroll
            for (int r = 0; r < 4; ++r)
                h0reg[j][r] = hidden[(size_t)(row + crow0 + r) * 512 + base + j * 16 + ccol];
        #pragma unroll
        for (int j = 0; j < 4; ++j) {
            int lc = j * 16 + ccol;
            bias_p1_0[j] = bh[(lc >> 5) * 512 + base + (lc & 31)];
        }
        #pragma unroll
        for (int j = 0; j < 2; ++j)
            bias_p2_0[j] = bh[1024 + base + j * 16 + ccol];
    } else {
        const int base = wid << 4;
        #pragma unroll
        for (int r = 0; r < 4; ++r)
            h1reg[r] = hidden[(size_t)BH_ + (size_t)(row + crow0 + r) * 512 + base + ccol];
        bias_p1_1[0] = bh[1536 + base + ccol];
        bias_p1_1[1] = bh[1536 + 512 + base + ccol];
        bias_p2_1 = bh[2560 + base + ccol];
    }
    __syncthreads();

    for (int s = 0; s <= 2 * T_ + 1; ++s) {
        int t = s >> 1;
        if ((s & 1) == 0) {
            if (isL0) {
                if (t < T_) {  // ---- L0-P1(t): r,f gates over 64 owned cols
                    const int base = wg << 5;
                    const unsigned short* hprev = h0bt + (size_t)t * BH_;
                    unsigned short* rh0 = rh0t + (size_t)t * BH_;
                    bf16x8 a[16];
                    #pragma unroll
                    for (int ks = 0; ks < 16; ++ks)
                        a[ks] = *(const bf16x8*)(hprev + (size_t)(row + lr) * 512 + ks * 32 + lk8);
                    float gxv[4][4];
                    #pragma unroll
                    for (int j = 0; j < 4; ++j) {
                        int lc = j * 16 + ccol;
                        const float* gx = gx0 + (size_t)(t * 3 + (lc >> 5)) * BH_ + base + (lc & 31);
                        #pragma unroll
                        for (int r = 0; r < 4; ++r)
                            gxv[j][r] = gx[(row + crow0 + r) * 512];
                    }
                    f32x4 acc[4] = {};
                    #pragma unroll
                    for (int ks = 0; ks < 16; ++ks) {
                        int kg = 4 * ks + hi;
                        #pragma unroll
                        for (int j = 0; j < 4; ++j) {
                            int c = j * 16 + lr;
                            bf16x8 b = *(const bf16x8*)(wlds + c * 512 + (kg ^ (c & 7)) * 8);
                            acc[j] = __builtin_amdgcn_mfma_f32_16x16x32_bf16(a[ks], b, acc[j], 0, 0, 0);
                        }
                    }
                    #pragma unroll
                    for (int j = 0; j < 4; ++j) {
                        int h = base + ((j & 1) * 16) + ccol;
                        #pragma unroll
                        for (int r = 0; r < 4; ++r) {
                            int b = row + crow0 + r;
                            float v = acc[j][r] + gxv[j][r] + bias_p1_0[j];
                            float sg = 1.f / (1.f + __expf(-v));
                            if (j < 2) store_pair_bf16(rh0, b * 512 + h, sg * h0reg[j][r], lane);
                            else       freg0[j - 2][r] = sg;
                        }
                    }
                }
            } else {
                int tc = t - 1;
                if (tc >= 0 && tc < T_) {  // ---- L1-P1(tc): 32 owned cols, K=1024
                    const int base = wid << 4;
                    const unsigned short* h0cur = h0bt + (size_t)(tc + 1) * BH_;
                    const unsigned short* h1prev = h1bfx + (size_t)tc * BH_;
                    unsigned short* rh1 = rh1t + (size_t)tc * BH_;
                    bf16x8 a0[16], a1[16];
                    #pragma unroll
                    for (int ks = 0; ks < 16; ++ks) {
                        a0[ks] = *(const bf16x8*)(h0cur + (size_t)(row + lr) * 512 + ks * 32 + lk8);
                        a1[ks] = *(const bf16x8*)(h1prev + (size_t)(row + lr) * 512 + ks * 32 + lk8);
                    }
                    f32x4 acc[2] = {};
                    #pragma unroll
                    for (int ks = 0; ks < 16; ++ks) {
                        int kg = 4 * ks + hi;
                        #pragma unroll
                        for (int j = 0; j < 2; ++j) {
                            int c = j * 16 + lr;
                            bf16x8 b = *(const bf16x8*)(wlds + c * 1024 + (kg ^ (c & 7)) * 8);
                            acc[j] = __builtin_amdgcn_mfma_f32_16x16x32_bf16(a0[ks], b, acc[j], 0, 0, 0);
                        }
                    }
                    #pragma unroll
                    for (int ks = 0; ks < 16; ++ks) {
                        int kg = 64 + 4 * ks + hi;
                        #pragma unroll
                        for (int j = 0; j < 2; ++j) {
                            int c = j * 16 + lr;
                            bf16x8 b = *(const bf16x8*)(wlds + c * 1024 + (kg ^ (c & 7)) * 8);
                            acc[j] = __builtin_amdgcn_mfma_f32_16x16x32_bf16(a1[ks], b, acc[j], 0, 0, 0);
                        }
                    }
                    #pragma unroll
                    for (int j = 0; j < 2; ++j) {
                        int h = base + ccol;
                        #pragma unroll
                        for (int r = 0; r < 4; ++r) {
                            int b = row + crow0 + r;
                            float v = acc[j][r] + bias_p1_1[j];
                            float sg = 1.f / (1.f + __expf(-v));
                            if (j == 0) store_pair_bf16(rh1, b * 512 + h, sg * h1reg[r], lane);
                            else        freg1[r] = sg;
                        }
                    }
                }
            }
        } else {
            if (isL0) {
                if (t < T_) {  // ---- L0-P2(t): candidate (32 cols) + blend
                    const int base = wg << 5;
                    const unsigned short* rh0 = rh0t + (size_t)t * BH_;
                    unsigned short* h0nx = h0bt + (size_t)(t + 1) * BH_;
                    bf16x8 a[16];
                    #pragma unroll
                    for (int ks = 0; ks < 16; ++ks)
                        a[ks] = *(const bf16x8*)(rh0 + (size_t)(row + lr) * 512 + ks * 32 + lk8);
                    float gxv[2][4];
                    #pragma unroll
                    for (int j = 0; j < 2; ++j) {
                        const float* gx = gx0 + (size_t)(t * 3 + 2) * BH_ + base + j * 16 + ccol;
                        #pragma unroll
                        for (int r = 0; r < 4; ++r)
                            gxv[j][r] = gx[(row + crow0 + r) * 512];
                    }
                    f32x4 acc[2] = {};
                    #pragma unroll
                    for (int ks = 0; ks < 16; ++ks) {
                        int kg = 4 * ks + hi;
                        #pragma unroll
                        for (int j = 0; j < 2; ++j) {
                            int c = 64 + j * 16 + lr;
                            bf16x8 b = *(const bf16x8*)(wlds + c * 512 + (kg ^ (c & 7)) * 8);
                            acc[j] = __builtin_amdgcn_mfma_f32_16x16x32_bf16(a[ks], b, acc[j], 0, 0, 0);
                        }
                    }
                    #pragma unroll
                    for (int j = 0; j < 2; ++j) {
                        int h = base + j * 16 + ccol;
                        #pragma unroll
                        for (int r = 0; r < 4; ++r) {
                            int b = row + crow0 + r;
                            float v = acc[j][r] + gxv[j][r] + bias_p2_0[j];
                            float tld = tanhf(v);
                            float hn = h0reg[j][r] + freg0[j][r] * (tld - h0reg[j][r]);
                            h0reg[j][r] = hn;
                            store_pair_bf16(h0nx, b * 512 + h, hn, lane);
                        }
                    }
                }
            } else {
                int tc = t - 1;
                if (tc >= 0 && tc < T_) {  // ---- L1-P2(tc): candidate (16 cols) + blend
                    const int base = wid << 4;
                    const unsigned short* h0cur = h0bt + (size_t)(tc + 1) * BH_;
                    const unsigned short* rh1 = rh1t + (size_t)tc * BH_;
                    unsigned short* h1nx = h1bfx + (size_t)(tc + 1) * BH_;
                    bf16x8 a0[16], a1[16];
                    #pragma unroll
                    for (int ks = 0; ks < 16; ++ks) {
                        a0[ks] = *(const bf16x8*)(h0cur + (size_t)(row + lr) * 512 + ks * 32 + lk8);
                        a1[ks] = *(const bf16x8*)(rh1 + (size_t)(row + lr) * 512 + ks * 32 + lk8);
                    }
                    f32x4 acc = {0.f, 0.f, 0.f, 0.f};
                    #pragma unroll
                    for (int ks = 0; ks < 16; ++ks) {
                        int kg = 4 * ks + hi;
                        int c = 32 + lr;
                        bf16x8 b = *(const bf16x8*)(wlds + c * 1024 + (kg ^ (c & 7)) * 8);
                        acc = __builtin_amdgcn_mfma_f32_16x16x32_bf16(a0[ks], b, acc, 0, 0, 0);
                    }
                    #pragma unroll
                    for (int ks = 0; ks < 16; ++ks) {
                        int kg = 64 + 4 * ks + hi;
                        int c = 32 + lr;
                        bf16x8 b = *(const bf16x8*)(wlds + c * 1024 + (kg ^ (c & 7)) * 8);
                        acc = __builtin_amdgcn_mfma_f32_16x16x32_bf16(a1[ks], b, acc, 0, 0, 0);
                    }
                    {
                        int h = base + ccol;
                        #pragma unroll
                        for (int r = 0; r < 4; ++r) {
                            int b = row + crow0 + r;
                            float v = acc[r] + bias_p2_1;
                            float tld = tanhf(v);
                            float hn = h1reg[r] + freg1[r] * (tld - h1reg[r]);
                            h1reg[r] = hn;
                            store_pair_bf16(h1nx, b * 512 + h, hn, lane);
                        }
                    }
                }
            }
        }
        grid_bar(flags, s + 1);
    }

    // final hidden from registers (each lane owns its elements)
    if (isL0) {
        const int base = wg << 5;
        #pragma unroll
        for (int j = 0; j < 2; ++j)
            #pragma unroll
            for (int r = 0; r < 4; ++r)
                hfinal_out[(size_t)(row + crow0 + r) * 512 + base + j * 16 + ccol] = h0reg[j][r];
    } else {
        const int base = wid << 4;
        #pragma unroll
        for (int r = 0; r < 4; ++r)
            hfinal_out[(size_t)BH_ + (size_t)(row + crow0 + r) * 512 + base + ccol] = h1reg[r];
    }
}

// ---------------------------------------------------------------- logits
#define MT_ (T_ * B_ / 128)          // 35 m-tiles
#define NT_ ((V_ + 127) / 128)       // 79 n-tiles
__global__ __launch_bounds__(256) void logits_gemm(
    const unsigned short* __restrict__ A, const unsigned short* __restrict__ Bw,
    const float* __restrict__ bout, float* __restrict__ C) {
    const int nwg = MT_ * NT_;
    const int q = nwg / 8, rr = nwg % 8;
    int bid = blockIdx.x;
    int xcd = bid % 8, idx = bid / 8;
    int wgid = (xcd < rr ? xcd * (q + 1) : rr * (q + 1) + (xcd - rr) * q) + idx;
    int n0 = (wgid / MT_) * 128;
    int m0 = (wgid % MT_) * 128;

    int wave = threadIdx.x >> 6, lane = threadIdx.x & 63;
    int wr = wave >> 1, wc = wave & 1;
    int am = m0 + wr * 64, bn = n0 + wc * 64;
    int lr = lane & 15, lk = (lane >> 4) * 8;

    f32x4 acc[4][4] = {};
    bf16x8 a[4], b[4], an[4], bnx[4];
    #pragma unroll
    for (int i = 0; i < 4; ++i)
        a[i] = *(const bf16x8*)(A + (size_t)(am + i * 16 + lr) * H_ + lk);
    #pragma unroll
    for (int j = 0; j < 4; ++j) {
        int colc = bn + j * 16 + lr; if (colc >= V_) colc = V_ - 1;
        b[j] = *(const bf16x8*)(Bw + (size_t)colc * H_ + lk);
    }
    for (int k0 = 0; k0 < H_; k0 += 32) {
        if (k0 + 32 < H_) {
            #pragma unroll
            for (int i = 0; i < 4; ++i)
                an[i] = *(const bf16x8*)(A + (size_t)(am + i * 16 + lr) * H_ + k0 + 32 + lk);
            #pragma unroll
            for (int j = 0; j < 4; ++j) {
                int colc = bn + j * 16 + lr; if (colc >= V_) colc = V_ - 1;
                bnx[j] = *(const bf16x8*)(Bw + (size_t)colc * H_ + k0 + 32 + lk);
            }
        }
        #pragma unroll
        for (int i = 0; i < 4; ++i)
            #pragma unroll
            for (int j = 0; j < 4; ++j)
                acc[i][j] = __builtin_amdgcn_mfma_f32_16x16x32_bf16(a[i], b[j], acc[i][j], 0, 0, 0);
        #pragma unroll
        for (int i = 0; i < 4; ++i) { a[i] = an[i]; b[i] = bnx[i]; }
    }
    int crow0 = (lane >> 4) * 4, ccol = lane & 15;
    #pragma unroll
    for (int j = 0; j < 4; ++j) {
        int col = bn + j * 16 + ccol;
        if (col >= V_) continue;
        float bv = bout[col];
        #pragma unroll
        for (int i = 0; i < 4; ++i) {
            #pragma unroll
            for (int r = 0; r < 4; ++r) {
                int row = am + i * 16 + crow0 + r;
                __builtin_nontemporal_store(acc[i][j][r] + bv, &C[(size_t)row * V_ + col]);
            }
        }
    }
}

// ---------------------------------------------------------------- launch
extern "C" void kernel_launch(void* const* d_in, const int* in_sizes, int n_in,
                              void* d_out, int out_size, void* d_ws, size_t ws_size,
                              hipStream_t stream) {
    const int*   inputs = (const int*)  d_in[0];
    const float* hidden = (const float*)d_in[1];
    const float* emb    = (const float*)d_in[2];
    const float* Wx0    = (const float*)d_in[3];
    const float* Wx     = (const float*)d_in[4];
    const float* Wh     = (const float*)d_in[5];
    const float* bh     = (const float*)d_in[6];
    const float* Wout   = (const float*)d_in[7];
    const float* bout   = (const float*)d_in[8];
    float* out = (float*)d_out;
    (void)in_sizes; (void)n_in; (void)out_size; (void)ws_size;

    char* ws = (char*)d_ws;
    size_t off = 0;
    auto alloc = [&](size_t bytes) -> void* {
        void* p = ws + off;
        off += (bytes + 255) & ~(size_t)255;
        return p;
    };
    unsigned short* embB   = (unsigned short*)alloc((size_t)V_ * KPAD * 2);
    unsigned short* wx0cat = (unsigned short*)alloc((size_t)1536 * KPAD * 2);
    unsigned short* WoutB  = (unsigned short*)alloc((size_t)V_ * H_ * 2);
    unsigned short* h1bfx  = (unsigned short*)alloc((size_t)(T_ + 1) * BH_ * 2);
    int* flags = (int*)alloc(NWG * 32 * 4);

    // gx0 [T][3][128][512] f32 in d_out (27.5 MB); rotated scan buffers after
    // it (also in d_out, overwritten by logits later). h1bfx in ws (logits input).
    float* gx0 = out;
    unsigned short* scr = (unsigned short*)(out + (size_t)T_ * 3 * BH_);
    unsigned short* h0bt = scr;                                   // 36*BH
    unsigned short* rh0t = scr + (size_t)(T_ + 1) * BH_;          // 35*BH
    unsigned short* rh1t = scr + (size_t)(2 * T_ + 1) * BH_;      // 35*BH

    prep_all<<<dim3(1024, 4), dim3(256), 0, stream>>>(
        emb, Wx0, hidden, Wout, embB, wx0cat, WoutB, h0bt, h1bfx, flags);
    xside_gemm<<<dim3(T_, 12), dim3(256), 0, stream>>>(inputs, embB, wx0cat, gx0);
    scan_kernel<<<dim3(NWG), dim3(512), 0, stream>>>(
        gx0, Wx, Wh, bh, hidden,
        h0bt, rh0t, rh1t, h1bfx, flags,
        out + (size_t)T_ * B_ * V_);
    logits_gemm<<<dim3(MT_ * NT_), dim3(256), 0, stream>>>(
        h1bfx + BH_, WoutB, bout, out);
}

// Round 12
// 653.028 us; speedup vs baseline: 4.4610x; 1.2397x over previous
//
#include <hip/hip_runtime.h>
#include <hip/hip_bf16.h>

#define T_ 35
#define B_ 128
#define E_ 200
#define H_ 512
#define L_ 2
#define V_ 10000
#define BH_ (B_ * H_)
#define KPAD 224
#define NCL 4            // independent row clusters (32 rows each)
#define CLW 48           // WGs per cluster
#define NWG (NCL * CLW)  // 192

typedef __attribute__((ext_vector_type(8))) short bf16x8;
typedef __attribute__((ext_vector_type(4))) float f32x4;

__device__ __forceinline__ unsigned short f2bf(float f) {
    union { float f; unsigned u; } c; c.f = f;
    unsigned r = c.u + 0x7FFF + ((c.u >> 16) & 1);
    return (unsigned short)(r >> 16);
}
__device__ __forceinline__ float bf2f(unsigned short u) {
    union { unsigned u; float f; } c; c.u = ((unsigned)u) << 16; return c.f;
}

__device__ __forceinline__ bf16x8 cvt8(const float* src) {
    float4 w0 = *(const float4*)src;
    float4 w1 = *(const float4*)(src + 4);
    bf16x8 v;
    v[0] = (short)f2bf(w0.x); v[1] = (short)f2bf(w0.y);
    v[2] = (short)f2bf(w0.z); v[3] = (short)f2bf(w0.w);
    v[4] = (short)f2bf(w1.x); v[5] = (short)f2bf(w1.y);
    v[6] = (short)f2bf(w1.z); v[7] = (short)f2bf(w1.w);
    return v;
}

// pair-pack bf16 -> one 4B relaxed agent-scope store (MALL-bypass).
__device__ __forceinline__ void store_pair_bf16(unsigned short* buf, int idx,
                                                float v, int lane) {
    float vn = __shfl_xor(v, 1);
    if ((lane & 1) == 0) {
        unsigned p = (unsigned)f2bf(v) | ((unsigned)f2bf(vn) << 16);
        __hip_atomic_store((unsigned*)(buf + idx), p,
                           __ATOMIC_RELAXED, __HIP_MEMORY_SCOPE_AGENT);
    }
}

// ---------------------------------------------------------------- prep
__global__ void prep_all(const float* __restrict__ emb, const float* __restrict__ Wx0,
                         const float* __restrict__ hidden, const float* __restrict__ Wout,
                         unsigned short* embB, unsigned short* wx0cat,
                         unsigned short* WoutB,
                         unsigned short* h0bt, unsigned short* h1bfx, int* flags) {
    int job = blockIdx.y;
    int stride = gridDim.x * blockDim.x;
    int i0 = blockIdx.x * blockDim.x + threadIdx.x;
    if (job == 0) {
        for (int i = i0; i < V_ * KPAD; i += stride) {
            int v = i / KPAD, k = i - v * KPAD;
            embB[i] = (k < E_) ? f2bf(emb[v * E_ + k]) : (unsigned short)0;
        }
    } else if (job == 1) {
        for (int i = i0; i < 1536 * KPAD; i += stride) {
            int n = i / KPAD, k = i - n * KPAD;
            wx0cat[i] = (k < E_) ? f2bf(Wx0[n * E_ + k]) : (unsigned short)0;
        }
    } else if (job == 2) {
        for (int i = i0; i < 2 * BH_; i += stride) {
            if (i < BH_) h0bt[i] = f2bf(hidden[i]);
            else         h1bfx[i - BH_] = f2bf(hidden[i]);
        }
        for (int i = i0; i < NWG * 32; i += stride) flags[i] = 0;
    } else {
        for (int i = i0; i < V_ * H_; i += stride) WoutB[i] = f2bf(Wout[i]);
    }
}

// ---------------------------------------------------------------- x-side GEMM
__global__ __launch_bounds__(256) void xside_gemm(
    const int* __restrict__ inputs, const unsigned short* __restrict__ embB,
    const unsigned short* __restrict__ wx0cat, float* __restrict__ gx0) {
    int m0 = blockIdx.x * 128, n0 = blockIdx.y * 128;
    int wave = threadIdx.x >> 6, lane = threadIdx.x & 63;
    int wr = wave >> 1, wc = wave & 1;
    int am = m0 + wr * 64, bn = n0 + wc * 64;
    int lr = lane & 15, lk = (lane >> 4) * 8;

    f32x4 acc[4][4] = {};
    int id[4];
    #pragma unroll
    for (int i = 0; i < 4; ++i) id[i] = inputs[am + i * 16 + lr];

    for (int k0 = 0; k0 < KPAD; k0 += 32) {
        bf16x8 a[4], b[4];
        #pragma unroll
        for (int i = 0; i < 4; ++i)
            a[i] = *(const bf16x8*)(embB + (size_t)id[i] * KPAD + k0 + lk);
        #pragma unroll
        for (int j = 0; j < 4; ++j)
            b[j] = *(const bf16x8*)(wx0cat + (size_t)(bn + j * 16 + lr) * KPAD + k0 + lk);
        #pragma unroll
        for (int i = 0; i < 4; ++i)
            #pragma unroll
            for (int j = 0; j < 4; ++j)
                acc[i][j] = __builtin_amdgcn_mfma_f32_16x16x32_bf16(a[i], b[j], acc[i][j], 0, 0, 0);
    }
    int crow0 = (lane >> 4) * 4, ccol = lane & 15;
    #pragma unroll
    for (int i = 0; i < 4; ++i) {
        #pragma unroll
        for (int r = 0; r < 4; ++r) {
            int row = am + i * 16 + crow0 + r;
            int t = row >> 7, b = row & 127;
            #pragma unroll
            for (int j = 0; j < 4; ++j) {
                int col = bn + j * 16 + ccol;
                int g = col >> 9, h = col & 511;
                gx0[((size_t)(t * 3 + g) * 128 + b) * 512 + h] = acc[i][j][r];
            }
        }
    }
}

// ---------------------------------------------------------------- scan
// Per-cluster fence-free barrier (48 flags, parallel arrivals, relaxed poll).
__device__ __forceinline__ void cl_bar(int* flb, int wgl, int gen) {
    __syncthreads();
    if (threadIdx.x == 0)
        __hip_atomic_store(flb + wgl * 32, gen,
                           __ATOMIC_RELAXED, __HIP_MEMORY_SCOPE_AGENT);
    if (threadIdx.x < CLW) {
        while (__hip_atomic_load(flb + threadIdx.x * 32, __ATOMIC_RELAXED,
                                 __HIP_MEMORY_SCOPE_AGENT) < gen)
            __builtin_amdgcn_s_sleep(1);
    }
    __syncthreads();
}

// Persistent scan: 4 independent 32-row clusters x 48 WGs x 512 thr.
// Cluster cl owns rows [cl*32, cl*32+32). Within a cluster:
//   wgl 0..15  = L0, 32 cols/gate (LDS [96][512] bf16, swizzled)
//   wgl 16..47 = L1, 16 cols/gate (LDS [48][1024] bf16, swizzled)
// L0 waves: (mt=wave>>2, nt=wave&3). P1: all 8 waves (tile mt x nt).
//   P2: waves nt>=2 (tile mt x (nt-2)) — f/h0 registers stay in-wave.
// L1 waves: P1: waves 0..3 (mt=w>>1, nt=w&1, full K=1024); P2: waves {1,3}
//   (reuse h0 a-frags from P1, f1/h1 registers in-wave).
__global__ __launch_bounds__(512) void scan_kernel(
    const float* __restrict__ gx0,
    const float* __restrict__ Wx, const float* __restrict__ Wh,
    const float* __restrict__ bh, const float* __restrict__ hidden,
    unsigned short* h0bt, unsigned short* rh0t, unsigned short* rh1t,
    unsigned short* h1bfx, int* flags, float* hfinal_out) {
    __shared__ unsigned short wlds[96 * 512];   // 96 KB

    const int tid = threadIdx.x;
    const int bx = blockIdx.x;
    const int cl = bx & 3;
    const int wgl = bx >> 2;
    const int lane = tid & 63;
    const int wave = tid >> 6;            // 0..7
    const int lr = lane & 15;
    const int hi = lane >> 4;             // 0..3
    const int lk8 = hi * 8;
    const int ccol = lane & 15;
    const int crow0 = hi * 4;
    const int R0 = cl * 32;

    const bool isL0 = (wgl < 16);
    const int wid = wgl - 16;
    int* flb = flags + cl * CLW * 32;

    // ---- one-time LDS weight staging (f32 -> bf16, kg ^= (col&7) swizzle) ----
    if (isL0) {
        for (int i = tid; i < 96 * 64; i += 512) {
            int lc = i >> 6, kg = i & 63;
            int g = lc >> 5, h = (wgl << 5) + (lc & 31);
            const float* src = Wh + (size_t)(g * 512 + h) * 512 + kg * 8;
            *(bf16x8*)(wlds + lc * 512 + (kg ^ (lc & 7)) * 8) = cvt8(src);
        }
    } else {
        for (int i = tid; i < 48 * 128; i += 512) {
            int lc = i >> 7, kg = i & 127;
            int g = lc >> 4, h = (wid << 4) + (lc & 15);
            const float* src = (kg < 64)
                ? Wx + (size_t)(g * 512 + h) * 512 + kg * 8
                : Wh + (size_t)(3 * 512 * 512) + (size_t)(g * 512 + h) * 512 + (kg - 64) * 8;
            *(bf16x8*)(wlds + lc * 1024 + (kg ^ (lc & 7)) * 8) = cvt8(src);
        }
    }

    // ---- per-wave tile mapping + register state ----
    // L0: mt = wave>>2 (row-tile), nt = wave&3 (col-tile of P1's 4 tiles)
    // L1: P1 waves<4: mt = wave>>1, nt = wave&1
    const int mt0 = wave >> 2, nt0 = wave & 3;
    const int mt1 = (wave >> 1) & 1, nt1 = wave & 1;
    float h0reg[4], freg0[4], bias_p1_0 = 0.f, bias_p2_0 = 0.f;
    float h1reg[4], freg1[4], bias_p1_1 = 0.f, bias_p2_1 = 0.f;
    bf16x8 a0keep[16];

    if (isL0) {
        const int base = wgl << 5;
        int g = nt0 >> 1;
        int hp1 = base + (nt0 & 1) * 16 + ccol;
        bias_p1_0 = bh[g * 512 + hp1];
        if (nt0 >= 2) {
            int hc = base + (nt0 - 2) * 16 + ccol;
            int rowg = R0 + mt0 * 16;
            #pragma unroll
            for (int r = 0; r < 4; ++r)
                h0reg[r] = hidden[(size_t)(rowg + crow0 + r) * 512 + hc];
            bias_p2_0 = bh[1024 + hc];
        }
    } else {
        const int base = wid << 4;
        int hc = base + ccol;
        if (wave < 4) {
            bias_p1_1 = bh[1536 + nt1 * 512 + hc];
            if (nt1 == 1) {
                int rowg = R0 + mt1 * 16;
                #pragma unroll
                for (int r = 0; r < 4; ++r)
                    h1reg[r] = hidden[(size_t)BH_ + (size_t)(rowg + crow0 + r) * 512 + hc];
                bias_p2_1 = bh[2560 + hc];
            }
        }
    }
    __syncthreads();

    for (int s = 0; s <= 2 * T_ + 1; ++s) {
        int t = s >> 1;
        if ((s & 1) == 0) {
            if (isL0) {
                if (t < T_) {  // ---- L0-P1(t): one 16x16 tile per wave
                    const int base = wgl << 5;
                    const int rowg = R0 + mt0 * 16;
                    const unsigned short* hprev = h0bt + (size_t)t * BH_;
                    unsigned short* rh0 = rh0t + (size_t)t * BH_;
                    bf16x8 a[16];
                    #pragma unroll
                    for (int ks = 0; ks < 16; ++ks)
                        a[ks] = *(const bf16x8*)(hprev + (size_t)(rowg + lr) * 512 + ks * 32 + lk8);
                    int g = nt0 >> 1;
                    int h = base + (nt0 & 1) * 16 + ccol;
                    float gxv[4];
                    {
                        const float* gx = gx0 + (size_t)(t * 3 + g) * BH_ + h;
                        #pragma unroll
                        for (int r = 0; r < 4; ++r)
                            gxv[r] = gx[(rowg + crow0 + r) * 512];
                    }
                    f32x4 acc = {0.f, 0.f, 0.f, 0.f};
                    #pragma unroll
                    for (int ks = 0; ks < 16; ++ks) {
                        int kg = 4 * ks + hi;
                        int c = nt0 * 16 + lr;
                        bf16x8 b = *(const bf16x8*)(wlds + c * 512 + (kg ^ (c & 7)) * 8);
                        acc = __builtin_amdgcn_mfma_f32_16x16x32_bf16(a[ks], b, acc, 0, 0, 0);
                    }
                    #pragma unroll
                    for (int r = 0; r < 4; ++r) {
                        int b = rowg + crow0 + r;
                        float v = acc[r] + gxv[r] + bias_p1_0;
                        float sg = 1.f / (1.f + __expf(-v));
                        if (nt0 < 2) {
                            float h0p = bf2f(hprev[(size_t)b * 512 + h]);
                            store_pair_bf16(rh0, b * 512 + h, sg * h0p, lane);
                        } else {
                            freg0[r] = sg;
                        }
                    }
                }
            } else {
                int tc = t - 1;
                if (tc >= 0 && tc < T_ && wave < 4) {  // ---- L1-P1(tc)
                    const int base = wid << 4;
                    const int rowg = R0 + mt1 * 16;
                    const unsigned short* h0cur = h0bt + (size_t)(tc + 1) * BH_;
                    const unsigned short* h1prev = h1bfx + (size_t)tc * BH_;
                    unsigned short* rh1 = rh1t + (size_t)tc * BH_;
                    bf16x8 a1[16];
                    #pragma unroll
                    for (int ks = 0; ks < 16; ++ks) {
                        a0keep[ks] = *(const bf16x8*)(h0cur + (size_t)(rowg + lr) * 512 + ks * 32 + lk8);
                        a1[ks] = *(const bf16x8*)(h1prev + (size_t)(rowg + lr) * 512 + ks * 32 + lk8);
                    }
                    f32x4 acc = {0.f, 0.f, 0.f, 0.f};
                    #pragma unroll
                    for (int ks = 0; ks < 16; ++ks) {
                        int kg = 4 * ks + hi;
                        int c = nt1 * 16 + lr;
                        bf16x8 b = *(const bf16x8*)(wlds + c * 1024 + (kg ^ (c & 7)) * 8);
                        acc = __builtin_amdgcn_mfma_f32_16x16x32_bf16(a0keep[ks], b, acc, 0, 0, 0);
                    }
                    #pragma unroll
                    for (int ks = 0; ks < 16; ++ks) {
                        int kg = 64 + 4 * ks + hi;
                        int c = nt1 * 16 + lr;
                        bf16x8 b = *(const bf16x8*)(wlds + c * 1024 + (kg ^ (c & 7)) * 8);
                        acc = __builtin_amdgcn_mfma_f32_16x16x32_bf16(a1[ks], b, acc, 0, 0, 0);
                    }
                    int h = base + ccol;
                    #pragma unroll
                    for (int r = 0; r < 4; ++r) {
                        int b = rowg + crow0 + r;
                        float v = acc[r] + bias_p1_1;
                        float sg = 1.f / (1.f + __expf(-v));
                        if (nt1 == 0) {
                            float h1p = bf2f(h1prev[(size_t)b * 512 + h]);
                            store_pair_bf16(rh1, b * 512 + h, sg * h1p, lane);
                        } else {
                            freg1[r] = sg;
                        }
                    }
                }
            }
        } else {
            if (isL0) {
                if (t < T_ && nt0 >= 2) {  // ---- L0-P2(t): waves nt0 in {2,3}
                    const int base = wgl << 5;
                    const int ntp = nt0 - 2;
                    const int rowg = R0 + mt0 * 16;
                    const unsigned short* rh0 = rh0t + (size_t)t * BH_;
                    unsigned short* h0nx = h0bt + (size_t)(t + 1) * BH_;
                    bf16x8 a[16];
                    #pragma unroll
                    for (int ks = 0; ks < 16; ++ks)
                        a[ks] = *(const bf16x8*)(rh0 + (size_t)(rowg + lr) * 512 + ks * 32 + lk8);
                    int h = base + ntp * 16 + ccol;
                    float gxv[4];
                    {
                        const float* gx = gx0 + (size_t)(t * 3 + 2) * BH_ + h;
                        #pragma unroll
                        for (int r = 0; r < 4; ++r)
                            gxv[r] = gx[(rowg + crow0 + r) * 512];
                    }
                    f32x4 acc = {0.f, 0.f, 0.f, 0.f};
                    #pragma unroll
                    for (int ks = 0; ks < 16; ++ks) {
                        int kg = 4 * ks + hi;
                        int c = 64 + ntp * 16 + lr;
                        bf16x8 b = *(const bf16x8*)(wlds + c * 512 + (kg ^ (c & 7)) * 8);
                        acc = __builtin_amdgcn_mfma_f32_16x16x32_bf16(a[ks], b, acc, 0, 0, 0);
                    }
                    #pragma unroll
                    for (int r = 0; r < 4; ++r) {
                        int b = rowg + crow0 + r;
                        float v = acc[r] + gxv[r] + bias_p2_0;
                        float tld = tanhf(v);
                        float hn = h0reg[r] + freg0[r] * (tld - h0reg[r]);
                        h0reg[r] = hn;
                        store_pair_bf16(h0nx, b * 512 + h, hn, lane);
                    }
                }
            } else {
                int tc = t - 1;
                if (tc >= 0 && tc < T_ && wave < 4 && nt1 == 1) {  // ---- L1-P2(tc)
                    const int base = wid << 4;
                    const int rowg = R0 + mt1 * 16;
                    const unsigned short* rh1 = rh1t + (size_t)tc * BH_;
                    unsigned short* h1nx = h1bfx + (size_t)(tc + 1) * BH_;
                    bf16x8 a1[16];
                    #pragma unroll
                    for (int ks = 0; ks < 16; ++ks)
                        a1[ks] = *(const bf16x8*)(rh1 + (size_t)(rowg + lr) * 512 + ks * 32 + lk8);
                    f32x4 acc = {0.f, 0.f, 0.f, 0.f};
                    #pragma unroll
                    for (int ks = 0; ks < 16; ++ks) {
                        int kg = 4 * ks + hi;
                        int c = 32 + lr;
                        bf16x8 b = *(const bf16x8*)(wlds + c * 1024 + (kg ^ (c & 7)) * 8);
                        acc = __builtin_amdgcn_mfma_f32_16x16x32_bf16(a0keep[ks], b, acc, 0, 0, 0);
                    }
                    #pragma unroll
                    for (int ks = 0; ks < 16; ++ks) {
                        int kg = 64 + 4 * ks + hi;
                        int c = 32 + lr;
                        bf16x8 b = *(const bf16x8*)(wlds + c * 1024 + (kg ^ (c & 7)) * 8);
                        acc = __builtin_amdgcn_mfma_f32_16x16x32_bf16(a1[ks], b, acc, 0, 0, 0);
                    }
                    int h = base + ccol;
                    #pragma unroll
                    for (int r = 0; r < 4; ++r) {
                        int b = rowg + crow0 + r;
                        float v = acc[r] + bias_p2_1;
                        float tld = tanhf(v);
                        float hn = h1reg[r] + freg1[r] * (tld - h1reg[r]);
                        h1reg[r] = hn;
                        store_pair_bf16(h1nx, b * 512 + h, hn, lane);
                    }
                }
            }
        }
        cl_bar(flb, wgl, s + 1);
    }

    // final hidden from registers
    if (isL0) {
        if (nt0 >= 2) {
            const int base = wgl << 5;
            int hc = base + (nt0 - 2) * 16 + ccol;
            int rowg = R0 + mt0 * 16;
            #pragma unroll
            for (int r = 0; r < 4; ++r)
                hfinal_out[(size_t)(rowg + crow0 + r) * 512 + hc] = h0reg[r];
        }
    } else if (wave < 4 && nt1 == 1) {
        const int base = wid << 4;
        int rowg = R0 + mt1 * 16;
        #pragma unroll
        for (int r = 0; r < 4; ++r)
            hfinal_out[(size_t)BH_ + (size_t)(rowg + crow0 + r) * 512 + base + ccol] = h1reg[r];
    }
}

// ---------------------------------------------------------------- logits
#define MT_ (T_ * B_ / 128)          // 35 m-tiles
#define NT_ ((V_ + 127) / 128)       // 79 n-tiles
__global__ __launch_bounds__(256) void logits_gemm(
    const unsigned short* __restrict__ A, const unsigned short* __restrict__ Bw,
    const float* __restrict__ bout, float* __restrict__ C) {
    const int nwg = MT_ * NT_;
    const int q = nwg / 8, rr = nwg % 8;
    int bid = blockIdx.x;
    int xcd = bid % 8, idx = bid / 8;
    int wgid = (xcd < rr ? xcd * (q + 1) : rr * (q + 1) + (xcd - rr) * q) + idx;
    int n0 = (wgid / MT_) * 128;
    int m0 = (wgid % MT_) * 128;

    int wave = threadIdx.x >> 6, lane = threadIdx.x & 63;
    int wr = wave >> 1, wc = wave & 1;
    int am = m0 + wr * 64, bn = n0 + wc * 64;
    int lr = lane & 15, lk = (lane >> 4) * 8;

    f32x4 acc[4][4] = {};
    bf16x8 a[4], b[4], an[4], bnx[4];
    #pragma unroll
    for (int i = 0; i < 4; ++i)
        a[i] = *(const bf16x8*)(A + (size_t)(am + i * 16 + lr) * H_ + lk);
    #pragma unroll
    for (int j = 0; j < 4; ++j) {
        int colc = bn + j * 16 + lr; if (colc >= V_) colc = V_ - 1;
        b[j] = *(const bf16x8*)(Bw + (size_t)colc * H_ + lk);
    }
    for (int k0 = 0; k0 < H_; k0 += 32) {
        if (k0 + 32 < H_) {
            #pragma unroll
            for (int i = 0; i < 4; ++i)
                an[i] = *(const bf16x8*)(A + (size_t)(am + i * 16 + lr) * H_ + k0 + 32 + lk);
            #pragma unroll
            for (int j = 0; j < 4; ++j) {
                int colc = bn + j * 16 + lr; if (colc >= V_) colc = V_ - 1;
                bnx[j] = *(const bf16x8*)(Bw + (size_t)colc * H_ + k0 + 32 + lk);
            }
        }
        #pragma unroll
        for (int i = 0; i < 4; ++i)
            #pragma unroll
            for (int j = 0; j < 4; ++j)
                acc[i][j] = __builtin_amdgcn_mfma_f32_16x16x32_bf16(a[i], b[j], acc[i][j], 0, 0, 0);
        #pragma unroll
        for (int i = 0; i < 4; ++i) { a[i] = an[i]; b[i] = bnx[i]; }
    }
    int crow0 = (lane >> 4) * 4, ccol = lane & 15;
    #pragma unroll
    for (int j = 0; j < 4; ++j) {
        int col = bn + j * 16 + ccol;
        if (col >= V_) continue;
        float bv = bout[col];
        #pragma unroll
        for (int i = 0; i < 4; ++i) {
            #pragma unroll
            for (int r = 0; r < 4; ++r) {
                int row = am + i * 16 + crow0 + r;
                __builtin_nontemporal_store(acc[i][j][r] + bv, &C[(size_t)row * V_ + col]);
            }
        }
    }
}

// ---------------------------------------------------------------- launch
extern "C" void kernel_launch(void* const* d_in, const int* in_sizes, int n_in,
                              void* d_out, int out_size, void* d_ws, size_t ws_size,
                              hipStream_t stream) {
    const int*   inputs = (const int*)  d_in[0];
    const float* hidden = (const float*)d_in[1];
    const float* emb    = (const float*)d_in[2];
    const float* Wx0    = (const float*)d_in[3];
    const float* Wx     = (const float*)d_in[4];
    const float* Wh     = (const float*)d_in[5];
    const float* bh     = (const float*)d_in[6];
    const float* Wout   = (const float*)d_in[7];
    const float* bout   = (const float*)d_in[8];
    float* out = (float*)d_out;
    (void)in_sizes; (void)n_in; (void)out_size; (void)ws_size;

    char* ws = (char*)d_ws;
    size_t off = 0;
    auto alloc = [&](size_t bytes) -> void* {
        void* p = ws + off;
        off += (bytes + 255) & ~(size_t)255;
        return p;
    };
    unsigned short* embB   = (unsigned short*)alloc((size_t)V_ * KPAD * 2);
    unsigned short* wx0cat = (unsigned short*)alloc((size_t)1536 * KPAD * 2);
    unsigned short* WoutB  = (unsigned short*)alloc((size_t)V_ * H_ * 2);
    unsigned short* h1bfx  = (unsigned short*)alloc((size_t)(T_ + 1) * BH_ * 2);
    int* flags = (int*)alloc(NWG * 32 * 4);

    // gx0 [T][3][128][512] f32 in d_out (27.5 MB); rotated scan buffers after
    // it (also in d_out, overwritten by logits later). h1bfx in ws (logits input).
    float* gx0 = out;
    unsigned short* scr = (unsigned short*)(out + (size_t)T_ * 3 * BH_);
    unsigned short* h0bt = scr;                                   // 36*BH
    unsigned short* rh0t = scr + (size_t)(T_ + 1) * BH_;          // 35*BH
    unsigned short* rh1t = scr + (size_t)(2 * T_ + 1) * BH_;      // 35*BH

    prep_all<<<dim3(1024, 4), dim3(256), 0, stream>>>(
        emb, Wx0, hidden, Wout, embB, wx0cat, WoutB, h0bt, h1bfx, flags);
    xside_gemm<<<dim3(T_, 12), dim3(256), 0, stream>>>(inputs, embB, wx0cat, gx0);
    scan_kernel<<<dim3(NWG), dim3(512), 0, stream>>>(
        gx0, Wx, Wh, bh, hidden,
        h0bt, rh0t, rh1t, h1bfx, flags,
        out + (size_t)T_ * B_ * V_);
    logits_gemm<<<dim3(MT_ * NT_), dim3(256), 0, stream>>>(
        h1bfx + BH_, WoutB, bout, out);
}

// Round 13
// 602.636 us; speedup vs baseline: 4.8340x; 1.0836x over previous
//
#include <hip/hip_runtime.h>
#include <hip/hip_bf16.h>

#define T_ 35
#define B_ 128
#define E_ 200
#define H_ 512
#define L_ 2
#define V_ 10000
#define BH_ (B_ * H_)
#define KPAD 224
#define NCL 4            // independent row clusters (32 rows each)
#define CLW 48           // WGs per cluster (16 L0 + 32 L1)
#define NWG (NCL * CLW)  // 192

typedef __attribute__((ext_vector_type(8))) short bf16x8;
typedef __attribute__((ext_vector_type(4))) float f32x4;

__device__ __forceinline__ unsigned short f2bf(float f) {
    union { float f; unsigned u; } c; c.f = f;
    unsigned r = c.u + 0x7FFF + ((c.u >> 16) & 1);
    return (unsigned short)(r >> 16);
}
__device__ __forceinline__ float bf2f(unsigned short u) {
    union { unsigned u; float f; } c; c.u = ((unsigned)u) << 16; return c.f;
}

__device__ __forceinline__ bf16x8 cvt8(const float* src) {
    float4 w0 = *(const float4*)src;
    float4 w1 = *(const float4*)(src + 4);
    bf16x8 v;
    v[0] = (short)f2bf(w0.x); v[1] = (short)f2bf(w0.y);
    v[2] = (short)f2bf(w0.z); v[3] = (short)f2bf(w0.w);
    v[4] = (short)f2bf(w1.x); v[5] = (short)f2bf(w1.y);
    v[6] = (short)f2bf(w1.z); v[7] = (short)f2bf(w1.w);
    return v;
}

// pair-pack bf16 -> one 4B relaxed agent-scope store (MALL-bypass).
__device__ __forceinline__ void store_pair_bf16(unsigned short* buf, int idx,
                                                float v, int lane) {
    float vn = __shfl_xor(v, 1);
    if ((lane & 1) == 0) {
        unsigned p = (unsigned)f2bf(v) | ((unsigned)f2bf(vn) << 16);
        __hip_atomic_store((unsigned*)(buf + idx), p,
                           __ATOMIC_RELAXED, __HIP_MEMORY_SCOPE_AGENT);
    }
}

// ---------------------------------------------------------------- prep
__global__ void prep_all(const float* __restrict__ emb, const float* __restrict__ Wx0,
                         const float* __restrict__ hidden, const float* __restrict__ Wout,
                         unsigned short* embB, unsigned short* wx0cat,
                         unsigned short* WoutB,
                         unsigned short* h0bt, unsigned short* h1bfx, int* flags) {
    int job = blockIdx.y;
    int stride = gridDim.x * blockDim.x;
    int i0 = blockIdx.x * blockDim.x + threadIdx.x;
    if (job == 0) {
        for (int i = i0; i < V_ * KPAD; i += stride) {
            int v = i / KPAD, k = i - v * KPAD;
            embB[i] = (k < E_) ? f2bf(emb[v * E_ + k]) : (unsigned short)0;
        }
    } else if (job == 1) {
        for (int i = i0; i < 1536 * KPAD; i += stride) {
            int n = i / KPAD, k = i - n * KPAD;
            wx0cat[i] = (k < E_) ? f2bf(Wx0[n * E_ + k]) : (unsigned short)0;
        }
    } else if (job == 2) {
        for (int i = i0; i < 2 * BH_; i += stride) {
            if (i < BH_) h0bt[i] = f2bf(hidden[i]);
            else         h1bfx[i - BH_] = f2bf(hidden[i]);
        }
        for (int i = i0; i < NWG * 32; i += stride) flags[i] = 0;
    } else {
        for (int i = i0; i < V_ * H_; i += stride) WoutB[i] = f2bf(Wout[i]);
    }
}

// ---------------------------------------------------------------- x-side GEMM
__global__ __launch_bounds__(256) void xside_gemm(
    const int* __restrict__ inputs, const unsigned short* __restrict__ embB,
    const unsigned short* __restrict__ wx0cat, float* __restrict__ gx0) {
    int m0 = blockIdx.x * 128, n0 = blockIdx.y * 128;
    int wave = threadIdx.x >> 6, lane = threadIdx.x & 63;
    int wr = wave >> 1, wc = wave & 1;
    int am = m0 + wr * 64, bn = n0 + wc * 64;
    int lr = lane & 15, lk = (lane >> 4) * 8;

    f32x4 acc[4][4] = {};
    int id[4];
    #pragma unroll
    for (int i = 0; i < 4; ++i) id[i] = inputs[am + i * 16 + lr];

    for (int k0 = 0; k0 < KPAD; k0 += 32) {
        bf16x8 a[4], b[4];
        #pragma unroll
        for (int i = 0; i < 4; ++i)
            a[i] = *(const bf16x8*)(embB + (size_t)id[i] * KPAD + k0 + lk);
        #pragma unroll
        for (int j = 0; j < 4; ++j)
            b[j] = *(const bf16x8*)(wx0cat + (size_t)(bn + j * 16 + lr) * KPAD + k0 + lk);
        #pragma unroll
        for (int i = 0; i < 4; ++i)
            #pragma unroll
            for (int j = 0; j < 4; ++j)
                acc[i][j] = __builtin_amdgcn_mfma_f32_16x16x32_bf16(a[i], b[j], acc[i][j], 0, 0, 0);
    }
    int crow0 = (lane >> 4) * 4, ccol = lane & 15;
    #pragma unroll
    for (int i = 0; i < 4; ++i) {
        #pragma unroll
        for (int r = 0; r < 4; ++r) {
            int row = am + i * 16 + crow0 + r;
            int t = row >> 7, b = row & 127;
            #pragma unroll
            for (int j = 0; j < 4; ++j) {
                int col = bn + j * 16 + ccol;
                int g = col >> 9, h = col & 511;
                gx0[((size_t)(t * 3 + g) * 128 + b) * 512 + h] = acc[i][j][r];
            }
        }
    }
}

// ---------------------------------------------------------------- scan
// Decoupled per-cluster pipelines: L0 (16 WGs) barriers only among itself;
// L1 (32 WGs) barriers among itself + lag-polls L0's flags. L0 never waits
// for L1. Rotated buffers -> no overwrite hazards at any lag.
__device__ __forceinline__ void bar_l0(int* flb, int wgl, int gen) {
    __syncthreads();
    if (threadIdx.x == 0)
        __hip_atomic_store(flb + wgl * 32, gen,
                           __ATOMIC_RELAXED, __HIP_MEMORY_SCOPE_AGENT);
    if (threadIdx.x < 16) {
        while (__hip_atomic_load(flb + threadIdx.x * 32, __ATOMIC_RELAXED,
                                 __HIP_MEMORY_SCOPE_AGENT) < gen)
            __builtin_amdgcn_s_sleep(1);
    }
    __syncthreads();
}

__device__ __forceinline__ void bar_l1(int* flb, int wid, int gen, int l0need) {
    __syncthreads();
    if (threadIdx.x == 0)
        __hip_atomic_store(flb + (16 + wid) * 32, gen,
                           __ATOMIC_RELAXED, __HIP_MEMORY_SCOPE_AGENT);
    if (threadIdx.x < 32) {
        while (__hip_atomic_load(flb + (16 + threadIdx.x) * 32, __ATOMIC_RELAXED,
                                 __HIP_MEMORY_SCOPE_AGENT) < gen)
            __builtin_amdgcn_s_sleep(1);
    } else if (threadIdx.x < 48) {
        while (__hip_atomic_load(flb + (threadIdx.x - 32) * 32, __ATOMIC_RELAXED,
                                 __HIP_MEMORY_SCOPE_AGENT) < l0need)
            __builtin_amdgcn_s_sleep(1);
    }
    __syncthreads();
}

__global__ __launch_bounds__(512) void scan_kernel(
    const float* __restrict__ gx0,
    const float* __restrict__ Wx, const float* __restrict__ Wh,
    const float* __restrict__ bh, const float* __restrict__ hidden,
    unsigned short* h0bt, unsigned short* rh0t, unsigned short* rh1t,
    unsigned short* h1bfx, int* flags, float* hfinal_out) {
    __shared__ unsigned short wlds[96 * 512];   // 96 KB

    const int tid = threadIdx.x;
    const int bx = blockIdx.x;
    const int cl = bx & 3;
    const int wgl = bx >> 2;
    const int lane = tid & 63;
    const int wave = tid >> 6;            // 0..7
    const int lr = lane & 15;
    const int hi = lane >> 4;             // 0..3
    const int lk8 = hi * 8;
    const int ccol = lane & 15;
    const int crow0 = hi * 4;
    const int R0 = cl * 32;

    const bool isL0 = (wgl < 16);
    const int wid = wgl - 16;
    int* flb = flags + cl * CLW * 32;

    // ---- one-time LDS weight staging (f32 -> bf16, kg ^= (col&7) swizzle) ----
    if (isL0) {
        for (int i = tid; i < 96 * 64; i += 512) {
            int lc = i >> 6, kg = i & 63;
            int g = lc >> 5, h = (wgl << 5) + (lc & 31);
            const float* src = Wh + (size_t)(g * 512 + h) * 512 + kg * 8;
            *(bf16x8*)(wlds + lc * 512 + (kg ^ (lc & 7)) * 8) = cvt8(src);
        }
    } else {
        for (int i = tid; i < 48 * 128; i += 512) {
            int lc = i >> 7, kg = i & 127;
            int g = lc >> 4, h = (wid << 4) + (lc & 15);
            const float* src = (kg < 64)
                ? Wx + (size_t)(g * 512 + h) * 512 + kg * 8
                : Wh + (size_t)(3 * 512 * 512) + (size_t)(g * 512 + h) * 512 + (kg - 64) * 8;
            *(bf16x8*)(wlds + lc * 1024 + (kg ^ (lc & 7)) * 8) = cvt8(src);
        }
    }

    // ---- per-wave tile mapping + register state ----
    const int mt0 = wave >> 2, nt0 = wave & 3;
    const int mt1 = (wave >> 1) & 1, nt1 = wave & 1;
    float h0reg[4], freg0[4], bias_p1_0 = 0.f, bias_p2_0 = 0.f;
    float h1reg[4], freg1[4], bias_p1_1 = 0.f, bias_p2_1 = 0.f;
    bf16x8 a0keep[16];

    if (isL0) {
        const int base = wgl << 5;
        int g = nt0 >> 1;
        int hp1 = base + (nt0 & 1) * 16 + ccol;
        bias_p1_0 = bh[g * 512 + hp1];
        if (nt0 >= 2) {
            int hc = base + (nt0 - 2) * 16 + ccol;
            int rowg = R0 + mt0 * 16;
            #pragma unroll
            for (int r = 0; r < 4; ++r)
                h0reg[r] = hidden[(size_t)(rowg + crow0 + r) * 512 + hc];
            bias_p2_0 = bh[1024 + hc];
        }
    } else {
        const int base = wid << 4;
        int hc = base + ccol;
        if (wave < 4) {
            bias_p1_1 = bh[1536 + nt1 * 512 + hc];
            if (nt1 == 1) {
                int rowg = R0 + mt1 * 16;
                #pragma unroll
                for (int r = 0; r < 4; ++r)
                    h1reg[r] = hidden[(size_t)BH_ + (size_t)(rowg + crow0 + r) * 512 + hc];
                bias_p2_1 = bh[2560 + hc];
            }
        }
    }
    __syncthreads();

    if (isL0) {
        // ================= L0 pipeline (16 WGs, own barrier) =================
        for (int s = 0; s < 2 * T_; ++s) {
            bar_l0(flb, wgl, s);   // peers completed s phases (inputs of s ready)
            int t = s >> 1;
            if ((s & 1) == 0) {
                // ---- L0-P1(t): one 16x16 tile per wave
                const int base = wgl << 5;
                const int rowg = R0 + mt0 * 16;
                const unsigned short* hprev = h0bt + (size_t)t * BH_;
                unsigned short* rh0 = rh0t + (size_t)t * BH_;
                bf16x8 a[16];
                #pragma unroll
                for (int ks = 0; ks < 16; ++ks)
                    a[ks] = *(const bf16x8*)(hprev + (size_t)(rowg + lr) * 512 + ks * 32 + lk8);
                int g = nt0 >> 1;
                int h = base + (nt0 & 1) * 16 + ccol;
                float gxv[4];
                {
                    const float* gx = gx0 + (size_t)(t * 3 + g) * BH_ + h;
                    #pragma unroll
                    for (int r = 0; r < 4; ++r)
                        gxv[r] = gx[(rowg + crow0 + r) * 512];
                }
                f32x4 accA = {0.f, 0.f, 0.f, 0.f}, accB = {0.f, 0.f, 0.f, 0.f};
                #pragma unroll
                for (int ks = 0; ks < 16; ks += 2) {
                    int c = nt0 * 16 + lr;
                    int kgA = 4 * ks + hi, kgB = 4 * (ks + 1) + hi;
                    bf16x8 bA = *(const bf16x8*)(wlds + c * 512 + (kgA ^ (c & 7)) * 8);
                    bf16x8 bB = *(const bf16x8*)(wlds + c * 512 + (kgB ^ (c & 7)) * 8);
                    accA = __builtin_amdgcn_mfma_f32_16x16x32_bf16(a[ks], bA, accA, 0, 0, 0);
                    accB = __builtin_amdgcn_mfma_f32_16x16x32_bf16(a[ks + 1], bB, accB, 0, 0, 0);
                }
                #pragma unroll
                for (int r = 0; r < 4; ++r) {
                    int b = rowg + crow0 + r;
                    float v = accA[r] + accB[r] + gxv[r] + bias_p1_0;
                    float sg = 1.f / (1.f + __expf(-v));
                    if (nt0 < 2) {
                        float h0p = bf2f(hprev[(size_t)b * 512 + h]);
                        store_pair_bf16(rh0, b * 512 + h, sg * h0p, lane);
                    } else {
                        freg0[r] = sg;
                    }
                }
            } else if (nt0 >= 2) {
                // ---- L0-P2(t): waves nt0 in {2,3}
                const int base = wgl << 5;
                const int ntp = nt0 - 2;
                const int rowg = R0 + mt0 * 16;
                const unsigned short* rh0 = rh0t + (size_t)t * BH_;
                unsigned short* h0nx = h0bt + (size_t)(t + 1) * BH_;
                bf16x8 a[16];
                #pragma unroll
                for (int ks = 0; ks < 16; ++ks)
                    a[ks] = *(const bf16x8*)(rh0 + (size_t)(rowg + lr) * 512 + ks * 32 + lk8);
                int h = base + ntp * 16 + ccol;
                float gxv[4];
                {
                    const float* gx = gx0 + (size_t)(t * 3 + 2) * BH_ + h;
                    #pragma unroll
                    for (int r = 0; r < 4; ++r)
                        gxv[r] = gx[(rowg + crow0 + r) * 512];
                }
                f32x4 accA = {0.f, 0.f, 0.f, 0.f}, accB = {0.f, 0.f, 0.f, 0.f};
                #pragma unroll
                for (int ks = 0; ks < 16; ks += 2) {
                    int c = 64 + ntp * 16 + lr;
                    int kgA = 4 * ks + hi, kgB = 4 * (ks + 1) + hi;
                    bf16x8 bA = *(const bf16x8*)(wlds + c * 512 + (kgA ^ (c & 7)) * 8);
                    bf16x8 bB = *(const bf16x8*)(wlds + c * 512 + (kgB ^ (c & 7)) * 8);
                    accA = __builtin_amdgcn_mfma_f32_16x16x32_bf16(a[ks], bA, accA, 0, 0, 0);
                    accB = __builtin_amdgcn_mfma_f32_16x16x32_bf16(a[ks + 1], bB, accB, 0, 0, 0);
                }
                #pragma unroll
                for (int r = 0; r < 4; ++r) {
                    int b = rowg + crow0 + r;
                    float v = accA[r] + accB[r] + gxv[r] + bias_p2_0;
                    float tld = tanhf(v);
                    float hn = h0reg[r] + freg0[r] * (tld - h0reg[r]);
                    h0reg[r] = hn;
                    store_pair_bf16(h0nx, b * 512 + h, hn, lane);
                }
            }
        }
        // publish completion (gen 70) so L1 can pass its final l0need
        __syncthreads();
        if (tid == 0)
            __hip_atomic_store(flb + wgl * 32, 2 * T_,
                               __ATOMIC_RELAXED, __HIP_MEMORY_SCOPE_AGENT);
        // final h0 from registers
        if (nt0 >= 2) {
            const int base = wgl << 5;
            int hc = base + (nt0 - 2) * 16 + ccol;
            int rowg = R0 + mt0 * 16;
            #pragma unroll
            for (int r = 0; r < 4; ++r)
                hfinal_out[(size_t)(rowg + crow0 + r) * 512 + hc] = h0reg[r];
        }
    } else {
        // ================= L1 pipeline (32 WGs, lags L0) =================
        for (int s = 0; s < 2 * T_; ++s) {
            int tc = s >> 1;
            int l0need = ((s & 1) == 0) ? (2 * tc + 2) : 0;
            bar_l1(flb, wid, s, l0need);
            if ((s & 1) == 0) {
                if (wave < 4) {  // ---- L1-P1(tc)
                    const int base = wid << 4;
                    const int rowg = R0 + mt1 * 16;
                    const unsigned short* h0cur = h0bt + (size_t)(tc + 1) * BH_;
                    const unsigned short* h1prev = h1bfx + (size_t)tc * BH_;
                    unsigned short* rh1 = rh1t + (size_t)tc * BH_;
                    bf16x8 a1[16];
                    #pragma unroll
                    for (int ks = 0; ks < 16; ++ks) {
                        a0keep[ks] = *(const bf16x8*)(h0cur + (size_t)(rowg + lr) * 512 + ks * 32 + lk8);
                        a1[ks] = *(const bf16x8*)(h1prev + (size_t)(rowg + lr) * 512 + ks * 32 + lk8);
                    }
                    f32x4 accA = {0.f, 0.f, 0.f, 0.f}, accB = {0.f, 0.f, 0.f, 0.f};
                    #pragma unroll
                    for (int ks = 0; ks < 16; ++ks) {
                        int kg = 4 * ks + hi;
                        int c = nt1 * 16 + lr;
                        bf16x8 b = *(const bf16x8*)(wlds + c * 1024 + (kg ^ (c & 7)) * 8);
                        accA = __builtin_amdgcn_mfma_f32_16x16x32_bf16(a0keep[ks], b, accA, 0, 0, 0);
                    }
                    #pragma unroll
                    for (int ks = 0; ks < 16; ++ks) {
                        int kg = 64 + 4 * ks + hi;
                        int c = nt1 * 16 + lr;
                        bf16x8 b = *(const bf16x8*)(wlds + c * 1024 + (kg ^ (c & 7)) * 8);
                        accB = __builtin_amdgcn_mfma_f32_16x16x32_bf16(a1[ks], b, accB, 0, 0, 0);
                    }
                    int h = base + ccol;
                    #pragma unroll
                    for (int r = 0; r < 4; ++r) {
                        int b = rowg + crow0 + r;
                        float v = accA[r] + accB[r] + bias_p1_1;
                        float sg = 1.f / (1.f + __expf(-v));
                        if (nt1 == 0) {
                            float h1p = bf2f(h1prev[(size_t)b * 512 + h]);
                            store_pair_bf16(rh1, b * 512 + h, sg * h1p, lane);
                        } else {
                            freg1[r] = sg;
                        }
                    }
                }
            } else {
                if (wave < 4 && nt1 == 1) {  // ---- L1-P2(tc)
                    const int base = wid << 4;
                    const int rowg = R0 + mt1 * 16;
                    const unsigned short* rh1 = rh1t + (size_t)tc * BH_;
                    unsigned short* h1nx = h1bfx + (size_t)(tc + 1) * BH_;
                    bf16x8 a1[16];
                    #pragma unroll
                    for (int ks = 0; ks < 16; ++ks)
                        a1[ks] = *(const bf16x8*)(rh1 + (size_t)(rowg + lr) * 512 + ks * 32 + lk8);
                    f32x4 accA = {0.f, 0.f, 0.f, 0.f}, accB = {0.f, 0.f, 0.f, 0.f};
                    #pragma unroll
                    for (int ks = 0; ks < 16; ++ks) {
                        int kg = 4 * ks + hi;
                        int c = 32 + lr;
                        bf16x8 b = *(const bf16x8*)(wlds + c * 1024 + (kg ^ (c & 7)) * 8);
                        accA = __builtin_amdgcn_mfma_f32_16x16x32_bf16(a0keep[ks], b, accA, 0, 0, 0);
                    }
                    #pragma unroll
                    for (int ks = 0; ks < 16; ++ks) {
                        int kg = 64 + 4 * ks + hi;
                        int c = 32 + lr;
                        bf16x8 b = *(const bf16x8*)(wlds + c * 1024 + (kg ^ (c & 7)) * 8);
                        accB = __builtin_amdgcn_mfma_f32_16x16x32_bf16(a1[ks], b, accB, 0, 0, 0);
                    }
                    int h = base + ccol;
                    #pragma unroll
                    for (int r = 0; r < 4; ++r) {
                        int b = rowg + crow0 + r;
                        float v = accA[r] + accB[r] + bias_p2_1;
                        float tld = tanhf(v);
                        float hn = h1reg[r] + freg1[r] * (tld - h1reg[r]);
                        h1reg[r] = hn;
                        store_pair_bf16(h1nx, b * 512 + h, hn, lane);
                    }
                }
            }
        }
        // final h1 from registers
        if (wave < 4 && nt1 == 1) {
            const int base = wid << 4;
            int rowg = R0 + mt1 * 16;
            #pragma unroll
            for (int r = 0; r < 4; ++r)
                hfinal_out[(size_t)BH_ + (size_t)(rowg + crow0 + r) * 512 + base + ccol] = h1reg[r];
        }
    }
}

// ---------------------------------------------------------------- logits
#define MT_ (T_ * B_ / 128)          // 35 m-tiles
#define NT_ ((V_ + 127) / 128)       // 79 n-tiles
__global__ __launch_bounds__(256) void logits_gemm(
    const unsigned short* __restrict__ A, const unsigned short* __restrict__ Bw,
    const float* __restrict__ bout, float* __restrict__ C) {
    const int nwg = MT_ * NT_;
    const int q = nwg / 8, rr = nwg % 8;
    int bid = blockIdx.x;
    int xcd = bid % 8, idx = bid / 8;
    int wgid = (xcd < rr ? xcd * (q + 1) : rr * (q + 1) + (xcd - rr) * q) + idx;
    int n0 = (wgid / MT_) * 128;
    int m0 = (wgid % MT_) * 128;

    int wave = threadIdx.x >> 6, lane = threadIdx.x & 63;
    int wr = wave >> 1, wc = wave & 1;
    int am = m0 + wr * 64, bn = n0 + wc * 64;
    int lr = lane & 15, lk = (lane >> 4) * 8;

    f32x4 acc[4][4] = {};
    bf16x8 a[4], b[4], an[4], bnx[4];
    #pragma unroll
    for (int i = 0; i < 4; ++i)
        a[i] = *(const bf16x8*)(A + (size_t)(am + i * 16 + lr) * H_ + lk);
    #pragma unroll
    for (int j = 0; j < 4; ++j) {
        int colc = bn + j * 16 + lr; if (colc >= V_) colc = V_ - 1;
        b[j] = *(const bf16x8*)(Bw + (size_t)colc * H_ + lk);
    }
    for (int k0 = 0; k0 < H_; k0 += 32) {
        if (k0 + 32 < H_) {
            #pragma unroll
            for (int i = 0; i < 4; ++i)
                an[i] = *(const bf16x8*)(A + (size_t)(am + i * 16 + lr) * H_ + k0 + 32 + lk);
            #pragma unroll
            for (int j = 0; j < 4; ++j) {
                int colc = bn + j * 16 + lr; if (colc >= V_) colc = V_ - 1;
                bnx[j] = *(const bf16x8*)(Bw + (size_t)colc * H_ + k0 + 32 + lk);
            }
        }
        #pragma unroll
        for (int i = 0; i < 4; ++i)
            #pragma unroll
            for (int j = 0; j < 4; ++j)
                acc[i][j] = __builtin_amdgcn_mfma_f32_16x16x32_bf16(a[i], b[j], acc[i][j], 0, 0, 0);
        #pragma unroll
        for (int i = 0; i < 4; ++i) { a[i] = an[i]; b[i] = bnx[i]; }
    }
    int crow0 = (lane >> 4) * 4, ccol = lane & 15;
    #pragma unroll
    for (int j = 0; j < 4; ++j) {
        int col = bn + j * 16 + ccol;
        if (col >= V_) continue;
        float bv = bout[col];
        #pragma unroll
        for (int i = 0; i < 4; ++i) {
            #pragma unroll
            for (int r = 0; r < 4; ++r) {
                int row = am + i * 16 + crow0 + r;
                __builtin_nontemporal_store(acc[i][j][r] + bv, &C[(size_t)row * V_ + col]);
            }
        }
    }
}

// ---------------------------------------------------------------- launch
extern "C" void kernel_launch(void* const* d_in, const int* in_sizes, int n_in,
                              void* d_out, int out_size, void* d_ws, size_t ws_size,
                              hipStream_t stream) {
    const int*   inputs = (const int*)  d_in[0];
    const float* hidden = (const float*)d_in[1];
    const float* emb    = (const float*)d_in[2];
    const float* Wx0    = (const float*)d_in[3];
    const float* Wx     = (const float*)d_in[4];
    const float* Wh     = (const float*)d_in[5];
    const float* bh     = (const float*)d_in[6];
    const float* Wout   = (const float*)d_in[7];
    const float* bout   = (const float*)d_in[8];
    float* out = (float*)d_out;
    (void)in_sizes; (void)n_in; (void)out_size; (void)ws_size;

    char* ws = (char*)d_ws;
    size_t off = 0;
    auto alloc = [&](size_t bytes) -> void* {
        void* p = ws + off;
        off += (bytes + 255) & ~(size_t)255;
        return p;
    };
    unsigned short* embB   = (unsigned short*)alloc((size_t)V_ * KPAD * 2);
    unsigned short* wx0cat = (unsigned short*)alloc((size_t)1536 * KPAD * 2);
    unsigned short* WoutB  = (unsigned short*)alloc((size_t)V_ * H_ * 2);
    unsigned short* h1bfx  = (unsigned short*)alloc((size_t)(T_ + 1) * BH_ * 2);
    int* flags = (int*)alloc(NWG * 32 * 4);

    // gx0 [T][3][128][512] f32 in d_out (27.5 MB); rotated scan buffers after
    // it (also in d_out, overwritten by logits later). h1bfx in ws (logits input).
    float* gx0 = out;
    unsigned short* scr = (unsigned short*)(out + (size_t)T_ * 3 * BH_);
    unsigned short* h0bt = scr;                                   // 36*BH
    unsigned short* rh0t = scr + (size_t)(T_ + 1) * BH_;          // 35*BH
    unsigned short* rh1t = scr + (size_t)(2 * T_ + 1) * BH_;      // 35*BH

    prep_all<<<dim3(1024, 4), dim3(256), 0, stream>>>(
        emb, Wx0, hidden, Wout, embB, wx0cat, WoutB, h0bt, h1bfx, flags);
    xside_gemm<<<dim3(T_, 12), dim3(256), 0, stream>>>(inputs, embB, wx0cat, gx0);
    scan_kernel<<<dim3(NWG), dim3(512), 0, stream>>>(
        gx0, Wx, Wh, bh, hidden,
        h0bt, rh0t, rh1t, h1bfx, flags,
        out + (size_t)T_ * B_ * V_);
    logits_gemm<<<dim3(MT_ * NT_), dim3(256), 0, stream>>>(
        h1bfx + BH_, WoutB, bout, out);
}